// Round 2
// baseline (112359.399 us; speedup 1.0000x reference)
//
#include <hip/hip_runtime.h>
#include <stdint.h>

#define TDEC 800
#define NBATCH 64
#define TE 512
#define ED 512
#define NMEL 80
#define PRE 256
#define AR 1024
#define AD 128

typedef unsigned short u16;
typedef __bf16 bf16x8 __attribute__((ext_vector_type(8)));
typedef float f32x4 __attribute__((ext_vector_type(4)));

struct Args {
  // inputs
  const float *mem, *dec_in; const int *mlen;
  const float *W1, *b1, *W2, *b2;
  const float *Wi_a, *Wh_a, *bi_a, *bh_a;
  const float *Wq, *Wm, *v_in, *Wloc, *Wld;
  const float *Wi_d, *Wh_d, *bi_d, *bh_d;
  const float *Wp, *bp, *Wg, *bg;
  // barrier control
  int *grp_cnt, *root_cnt, *gen_root, *gen_grp;
  // state: block-major h (ab=attn h, db=dec h), row-major ctx
  // ab/db: [2][256 blk][64 b][4 cells] u16 ; hctx: [2][64 b][512] u16
  u16 *ab, *db, *hctx;
  // staged data
  u16 *x_all, *pmem_bf, *mem_bf, *hid_bf;
  u16 *WaSwz, *WdSwz, *WqT, *WpgSwz, *U2Swz;
  float *bias_a, *bias_d, *bpg;
  // outputs
  float *out_mel, *out_gate, *out_align;
};

__device__ __forceinline__ float b2f(u16 h){ return __uint_as_float(((uint32_t)h) << 16); }
__device__ __forceinline__ u16 f2b(float f){
  uint32_t u = __float_as_uint(f);
  uint32_t r = (u + 0x7fffu + ((u >> 16) & 1u)) >> 16;
  return (u16)r;
}
__device__ __forceinline__ float sigm(float x){ return 1.f / (1.f + __expf(-x)); }
__device__ __forceinline__ float tanh_(float x){ float e = __expf(2.f*x); return 1.f - 2.f/(e + 1.f); }

__device__ __forceinline__ f32x4 mfma16(bf16x8 a, bf16x8 b, f32x4 c){
  return __builtin_amdgcn_mfma_f32_16x16x32_bf16(a, b, c, 0, 0, 0);
}
__device__ __forceinline__ bf16x8 ldf(const u16* p){ return *(const bf16x8*)p; }

// ---------------- hierarchical grid barrier (unchanged, proven) --------------
__device__ void gbar(const Args& A, int blk, int tid, int bt){
  __syncthreads();
  if (tid == 0){
    __builtin_amdgcn_fence(__ATOMIC_RELEASE, "agent");
    int g = blk >> 5;
    int old = __hip_atomic_fetch_add(&A.grp_cnt[g*16], 1, __ATOMIC_RELAXED, __HIP_MEMORY_SCOPE_AGENT);
    if (old == bt*32 - 1){
      int ro = __hip_atomic_fetch_add(&A.root_cnt[0], 1, __ATOMIC_RELAXED, __HIP_MEMORY_SCOPE_AGENT);
      if (ro == bt*8 - 1){
        __hip_atomic_store(&A.gen_root[0], bt, __ATOMIC_RELAXED, __HIP_MEMORY_SCOPE_AGENT);
      } else {
        while (__hip_atomic_load(&A.gen_root[0], __ATOMIC_RELAXED, __HIP_MEMORY_SCOPE_AGENT) < bt)
          __builtin_amdgcn_s_sleep(2);
      }
      __hip_atomic_store(&A.gen_grp[g*16], bt, __ATOMIC_RELAXED, __HIP_MEMORY_SCOPE_AGENT);
    } else {
      while (__hip_atomic_load(&A.gen_grp[g*16], __ATOMIC_RELAXED, __HIP_MEMORY_SCOPE_AGENT) < bt)
        __builtin_amdgcn_s_sleep(4);
    }
    __builtin_amdgcn_fence(__ATOMIC_ACQUIRE, "agent");
  }
  __syncthreads();
}

// ---------------- Phase 1: full-K gate GEMM (16 cols/block, B in LDS) --------
// WHICH=0 attn (K=1792, 56 kt), WHICH=1 dec (K=2560, 80 kt)
template<int WHICH>
__device__ __forceinline__ void gemm16c(const Args& A, int t, int bn, int tid,
                                        const u16* sB, float* sG){
  const int pc = t & 1, pp = (t + 1) & 1;
  const int wave = tid >> 6, lane = tid & 63;
  const int row = wave*16 + (lane & 15);
  const int kg = (lane >> 4) << 3;
  const u16* abP  = A.ab + (size_t)pp * 65536;            // ah(t-1), block-major
  const u16* dbP  = A.db + (size_t)pc * 65536;            // dh(t-2), block-major
  const u16* ctxP = A.hctx + (size_t)pp * NBATCH * 512 + (size_t)row * 512;  // ctx(t-1)
  const u16* x0   = A.x_all + ((size_t)t * NBATCH + row) * PRE;
  f32x4 accE = {0.f,0.f,0.f,0.f}, accO = accE;
  #pragma unroll
  for (int kk = 0; kk < (WHICH ? 80 : 56); ++kk){
    bf16x8 a;
    if (WHICH == 0){
      if (kk < 8){
        a = ldf(x0 + kk*32 + kg);
      } else if (kk < 24){
        a = ldf(ctxP + kk*32 + kg - 256);
      } else {
        int c0 = kk*32 + kg - 768;
        const u16* p = abP + (((size_t)(c0 >> 2)) << 8) + (row << 2);
        union { uint2 u[2]; bf16x8 v; } af;
        af.u[0] = *(const uint2*)p; af.u[1] = *(const uint2*)(p + 256);
        a = af.v;
      }
    } else {
      if (kk < 32){
        int c0 = kk*32 + kg;
        const u16* p = abP + (((size_t)(c0 >> 2)) << 8) + (row << 2);
        union { uint2 u[2]; bf16x8 v; } af;
        af.u[0] = *(const uint2*)p; af.u[1] = *(const uint2*)(p + 256);
        a = af.v;
      } else if (kk < 48){
        a = ldf(ctxP + kk*32 + kg - 1024);
      } else {
        int c0 = kk*32 + kg - 1536;
        const u16* p = dbP + (((size_t)(c0 >> 2)) << 8) + (row << 2);
        union { uint2 u[2]; bf16x8 v; } af;
        af.u[0] = *(const uint2*)p; af.u[1] = *(const uint2*)(p + 256);
        a = af.v;
      }
    }
    bf16x8 w = *(const bf16x8*)(sB + ((size_t)kk*64 + lane)*8);
    if (kk & 1) accO = mfma16(a, w, accO);
    else        accE = mfma16(a, w, accE);
  }
  f32x4 acc = accE + accO;
  int r0 = wave*16 + ((lane >> 4) << 2), col = lane & 15;
  #pragma unroll
  for (int r = 0; r < 4; ++r) sG[(r0 + r)*17 + col] = acc[r];
}

// fused LSTM pointwise: thread tid owns (bb = tid&63, cell = 4*bn + tid>>6)
template<int WHICH>
__device__ __forceinline__ void pwise(const Args& A, int t, int bn, int tid,
                                      const float* sG, const float* b4, float& cst){
  const int pc = t & 1, pp = (t + 1) & 1;
  int bb = tid & 63, ci = tid >> 6;
  int j4 = ci * 4;
  float gi = sG[bb*17 + j4 + 0] + b4[0];
  float gf = sG[bb*17 + j4 + 1] + b4[1];
  float gg = sG[bb*17 + j4 + 2] + b4[2];
  float go = sG[bb*17 + j4 + 3] + b4[3];
  float cn = sigm(gf) * cst + sigm(gi) * tanh_(gg);
  cst = cn;
  float h = sigm(go) * tanh_(cn);
  u16* dst = (WHICH ? A.db + (size_t)pp*65536 : A.ab + (size_t)pc*65536)
             + (size_t)bn*256 + bb*4 + ci;
  *dst = f2b(h);
}

// ---------------- P3 pieces (single block per b) -----------------------------
__device__ __forceinline__ void loc_chunk(const float* s_aw, const float* s_awc,
                                          int tb, int tid, u16* sLoc, const bf16x8* U2reg){
  int wave = tid >> 6, lane = tid & 63;
  int tg0 = tb + wave*16 + (lane & 15);
  int kk0 = (lane >> 4) << 3;
  f32x4 acc[8];
  #pragma unroll
  for (int nt = 0; nt < 8; ++nt) acc[nt] = f32x4{0.f,0.f,0.f,0.f};
  #pragma unroll
  for (int kt = 0; kt < 2; ++kt){
    const float* src = kt ? s_awc : s_aw;
    int base = tg0 - 15 + kk0;
    union { u16 h[8]; bf16x8 v; } af;
    #pragma unroll
    for (int j = 0; j < 8; ++j){
      int idx = base + j;
      float f = (idx >= 0 && idx < TE) ? src[idx] : 0.f;
      af.h[j] = f2b(f);
    }
    #pragma unroll
    for (int nt = 0; nt < 8; ++nt) acc[nt] = mfma16(af.v, U2reg[kt*8 + nt], acc[nt]);
  }
  int rrow = wave*16 + ((lane>>4)<<2);
  #pragma unroll
  for (int nt = 0; nt < 8; ++nt){
    int d = nt*16 + (lane & 15);
    #pragma unroll
    for (int r = 0; r < 4; ++r) sLoc[(rrow + r)*132 + d] = f2b(acc[nt][r]);
  }
}

__device__ __forceinline__ float e_chunk(const Args& A, int b, int tb, int tid,
                                         const u16* sLoc, const float* s_pq,
                                         const float* s_v, float* s_exp, int mlen){
  int tl = tid >> 2, h4 = tid & 3;
  int tg = tb + tl;
  int d0 = h4 * 32;
  const u16* prow = A.pmem_bf + ((size_t)b*TE + tg)*AD + d0;
  const u16* lrow = sLoc + tl*132 + d0;
  float s = 0.f;
  #pragma unroll
  for (int dq = 0; dq < 4; ++dq){
    bf16x8 pv = ldf(prow + dq*8);
    bf16x8 lv = *(const bf16x8*)(lrow + dq*8);
    #pragma unroll
    for (int j = 0; j < 8; ++j){
      int d = d0 + dq*8 + j;
      float arg = s_pq[d] + (float)lv[j] + (float)pv[j];
      s += tanh_(arg) * s_v[d];
    }
  }
  s += __shfl_xor(s, 1); s += __shfl_xor(s, 2);
  float ex = 0.f;
  if (h4 == 0 && tg < mlen) ex = __expf(s);
  if (h4 == 0) s_exp[tg] = ex;
  return ex;
}

__device__ __forceinline__ void ctx64(const Args& A, int t, int b, int tid,
                                      const float* s_aw, int imax){
  int wave = tid >> 6, lane = tid & 63;
  int dseg = lane & 15, rr = lane >> 4;
  const u16* mb = A.mem_bf + ((size_t)b*TE)*ED + wave*128 + dseg*8;
  float a[8] = {0.f,0.f,0.f,0.f,0.f,0.f,0.f,0.f};
  #pragma unroll 8
  for (int i = 0; i < imax; ++i){
    int tt = i*4 + rr;
    float wt = s_aw[tt];
    bf16x8 mv = ldf(mb + (size_t)tt * ED);
    #pragma unroll
    for (int j = 0; j < 8; ++j) a[j] += wt * (float)mv[j];
  }
  #pragma unroll
  for (int j = 0; j < 8; ++j){ a[j] += __shfl_xor(a[j], 16); a[j] += __shfl_xor(a[j], 32); }
  if (lane < 16){
    union { u16 h[8]; uint4 u; } o;
    #pragma unroll
    for (int j = 0; j < 8; ++j) o.h[j] = f2b(a[j]);
    *(uint4*)(A.hctx + (size_t)(t&1)*NBATCH*512 + (size_t)b*512 + wave*128 + dseg*8) = o.u;
  }
}

__device__ __forceinline__ void proj_unit(const Args& A, int t, int ns, int tid){
  const int pp = (t + 1) & 1;
  int wave = tid >> 6, lane = tid & 63;
  int m = wave*16 + (lane & 15), kg = (lane >> 4) << 3;
  const u16* dbP = A.db + (size_t)pp * 65536;
  const u16* cxP = A.hctx + (size_t)pp * NBATCH * 512 + (size_t)m * 512;
  int n = ns*16 + (lane & 15);
  float bv = A.bpg[n];
  f32x4 acc = {bv, bv, bv, bv};
  #pragma unroll
  for (int kt = 0; kt < 48; ++kt){
    bf16x8 af;
    if (kt < 32){
      int c0 = kt*32 + kg;
      const u16* p = dbP + (((size_t)(c0 >> 2)) << 8) + (m << 2);
      union { uint2 u[2]; bf16x8 v; } u_;
      u_.u[0] = *(const uint2*)p; u_.u[1] = *(const uint2*)(p + 256);
      af = u_.v;
    } else {
      af = ldf(cxP + kt*32 + kg - 1024);
    }
    bf16x8 bb = ldf(A.WpgSwz + (((size_t)ns*48 + kt)*64 + lane)*8);
    acc = mfma16(af, bb, acc);
  }
  int r0 = wave*16 + ((lane>>4)<<2);
  #pragma unroll
  for (int r = 0; r < 4; ++r){
    int bb2 = r0 + r;
    if (n < 80)       A.out_mel[((size_t)bb2*TDEC + (t-1))*NMEL + n] = acc[r];
    else if (n == 80) A.out_gate[(size_t)bb2*TDEC + (t-1)] = acc[r];
  }
}

// ---------------- main persistent kernel -------------------------------------
__global__ __launch_bounds__(256, 1) void k_main(Args A){
  __shared__ u16 sWa[28672];                 // 56 kt x 512     (57,344 B)
  __shared__ u16 sWd[40960];                 // 80 kt x 512     (81,920 B)
  __shared__ __align__(16) char sBuf[16896]; // sGa|sGd (P1) / sLoc+scratch (P3)
  __shared__ float s_aw[512], s_awc[512], s_exp[512];
  __shared__ float s_pq[128], s_v[128];
  float* sGa = (float*)sBuf;
  float* sGd = (float*)(sBuf + 4352);
  u16*   sLoc = (u16*)sBuf;
  float* sF   = (float*)sBuf;
  const int bn = blockIdx.x, tid = threadIdx.x;
  const int b = bn;
  // stage this block's 16-col weight slices (persist all 800 steps)
  {
    const uint4* ga = (const uint4*)(A.WaSwz + (size_t)bn*28672);
    for (int i = tid; i < 3584; i += 256) ((uint4*)sWa)[i] = ga[i];
    const uint4* gd = (const uint4*)(A.WdSwz + (size_t)bn*40960);
    for (int i = tid; i < 5120; i += 256) ((uint4*)sWd)[i] = gd[i];
  }
  if (tid < 128) s_v[tid] = A.v_in[tid];
  for (int i = tid; i < 512; i += 256){ s_aw[i] = 0.f; s_awc[i] = 0.f; s_exp[i] = 0.f; }
  bf16x8 U2reg[16];
  #pragma unroll
  for (int kt = 0; kt < 2; ++kt)
    #pragma unroll
    for (int nt = 0; nt < 8; ++nt)
      U2reg[kt*8 + nt] = ldf(A.U2Swz + ((size_t)((nt*2 + kt)*64 + (tid & 63)))*8);
  float ba4[4], bd4[4];
  {
    int cb = bn*16 + (tid >> 6)*4;
    #pragma unroll
    for (int g = 0; g < 4; ++g){ ba4[g] = A.bias_a[cb+g]; bd4[g] = A.bias_d[cb+g]; }
  }
  float c_a = 0.f, c_d = 0.f;
  const int mlen = (bn < 64) ? A.mlen[bn] : 0;
  const int nch  = (mlen + 63) >> 6;
  const int imax = (mlen + 3) >> 2;
  __syncthreads();
  int bt = 0;
  #pragma unroll 1
  for (int t = 0; t <= TDEC; ++t){
    // ---- Phase 1: both LSTM gate GEMMs, fully in-block ----
    if (t < TDEC) gemm16c<0>(A, t, bn, tid, sWa, sGa);
    if (t >= 1)   gemm16c<1>(A, t, bn, tid, sWd, sGd);
    __syncthreads();
    if (t < TDEC) pwise<0>(A, t, bn, tid, sGa, ba4, c_a);
    if (t >= 1)   pwise<1>(A, t, bn, tid, sGd, bd4, c_d);
    gbar(A, bn, tid, ++bt);
    // ---- Phase 3 ----
    if (t < TDEC){
      if (bn < 64){
        const int pc = t & 1;
        // pq[b,:] = ah(t) row b  @ Wq^T   (local, redundant per block)
        {
          const int d = tid & 127, half = tid >> 7;
          const u16* wrow = A.WqT + (size_t)d*1024 + half*512;
          const u16* abP = A.ab + (size_t)pc * 65536;
          float acc = 0.f;
          #pragma unroll 8
          for (int kk = 0; kk < 64; ++kk){
            const u16* p = abP + (((size_t)(half*128 + 2*kk)) << 8) + b*4;
            union { uint2 u[2]; bf16x8 v; } af;
            af.u[0] = *(const uint2*)p; af.u[1] = *(const uint2*)(p + 256);
            bf16x8 wv = ldf(wrow + kk*8);
            #pragma unroll
            for (int j = 0; j < 8; ++j) acc += (float)wv[j] * (float)af.v[j];
          }
          sF[tid] = acc;
        }
        __syncthreads();
        if (tid < 128) s_pq[tid] = sF[tid] + sF[tid + 128];
        __syncthreads();
        // 8x {loc conv -> e/tanh} chunks, all LDS-local
        float ws = 0.f;
        #pragma unroll 1
        for (int ch = 0; ch < nch; ++ch){
          loc_chunk(s_aw, s_awc, ch*64, tid, sLoc, U2reg);
          __syncthreads();
          ws += e_chunk(A, b, ch*64, tid, sLoc, s_pq, s_v, s_exp, mlen);
          __syncthreads();
        }
        // softmax denominator, in-block
        #pragma unroll
        for (int o = 32; o >= 1; o >>= 1) ws += __shfl_xor(ws, o);
        if ((tid & 63) == 0) sF[tid >> 6] = ws;
        __syncthreads();
        float inv = 1.f / (sF[0] + sF[1] + sF[2] + sF[3]);
        for (int i = tid; i < TE; i += 256){
          float awt = s_exp[i] * inv;
          s_aw[i] = awt;
          s_awc[i] += awt;
          A.out_align[((size_t)b*TDEC + t)*TE + i] = awt;
        }
        __syncthreads();
        ctx64(A, t, b, tid, s_aw, imax);
      } else if (bn >= 72 && bn < 78 && t >= 1){
        proj_unit(A, t, bn - 72, tid);
      }
      gbar(A, bn, tid, ++bt);
    } else {
      if (bn >= 72 && bn < 78) proj_unit(A, t, bn - 72, tid);
    }
  }
}

// ---------------- setup kernels ----------------------------------------------
__global__ void k_prenet1(Args A){
  __shared__ float din[8 * 80];
  int g0 = blockIdx.x * 8;
  for (int idx = threadIdx.x; idx < 640; idx += 256){
    int r = idx / 80, k = idx % 80;
    int row = g0 + r;
    int t = row >> 6, b = row & 63;
    din[idx] = (t == 0) ? 0.f : A.dec_in[((size_t)(t - 1) * NBATCH + b) * NMEL + k];
  }
  __syncthreads();
  int j = threadIdx.x;
  float acc[8] = {0,0,0,0,0,0,0,0};
  for (int k = 0; k < 80; ++k){
    float w = A.W1[(size_t)j * 80 + k];
    #pragma unroll
    for (int r = 0; r < 8; ++r) acc[r] += w * din[r * 80 + k];
  }
  float bb = A.b1[j];
  #pragma unroll
  for (int r = 0; r < 8; ++r){
    float vx = acc[r] + bb; if (vx < 0.f) vx = 0.f;
    A.hid_bf[(size_t)(g0 + r) * PRE + j] = f2b(vx);
  }
}

__global__ void k_prenet2(Args A){
  __shared__ float hrow[8 * 256];
  int g0 = blockIdx.x * 8;
  for (int idx = threadIdx.x; idx < 2048; idx += 256){
    int r = idx >> 8, k = idx & 255;
    hrow[idx] = b2f(A.hid_bf[(size_t)(g0 + r) * PRE + k]);
  }
  __syncthreads();
  int j = threadIdx.x;
  float acc[8] = {0,0,0,0,0,0,0,0};
  for (int k = 0; k < 256; ++k){
    float w = A.W2[(size_t)j * PRE + k];
    #pragma unroll
    for (int r = 0; r < 8; ++r) acc[r] += w * hrow[r * 256 + k];
  }
  float bb = A.b2[j];
  #pragma unroll
  for (int r = 0; r < 8; ++r){
    float vx = acc[r] + bb; if (vx < 0.f) vx = 0.f;
    A.x_all[(size_t)(g0 + r) * PRE + j] = f2b(vx);
  }
}

__global__ void k_membf(Args A){
  size_t n = (size_t)NBATCH * TE * ED;
  for (size_t i = (size_t)blockIdx.x * 256 + threadIdx.x; i < n; i += (size_t)gridDim.x * 256)
    A.mem_bf[i] = f2b(A.mem[i]);
}

__global__ void k_pmem(Args A){
  __shared__ float mrow[8 * 512];
  int g0 = blockIdx.x * 8;
  for (int idx = threadIdx.x; idx < 4096; idx += 256){
    int r = idx >> 9, k = idx & 511;
    mrow[idx] = A.mem[(size_t)(g0 + r) * ED + k];
  }
  __syncthreads();
  int d = threadIdx.x & 127, hh = threadIdx.x >> 7;
  float acc[4] = {0,0,0,0};
  for (int k = 0; k < 512; ++k){
    float w = A.Wm[(size_t)d * ED + k];
    #pragma unroll
    for (int r = 0; r < 4; ++r) acc[r] += w * mrow[(hh * 4 + r) * 512 + k];
  }
  #pragma unroll
  for (int r = 0; r < 4; ++r)
    A.pmem_bf[(size_t)(g0 + hh * 4 + r) * AD + d] = f2b(acc[r]);
}

__global__ void k_swz(Args A){
  const size_t Na = 917504, Nd = 1310720, Nq = 16384, Npg = 18432, Nu2 = 1024;
  const size_t NT = Na + Nd + Nq + Npg + Nu2;
  size_t id = (size_t)blockIdx.x * 256 + threadIdx.x;
  if (id >= NT + 8288) return;
  if (id < NT){
    int which; size_t lid; int NKT; u16* dst;
    if (id < Na){ which = 0; lid = id; NKT = 56; dst = A.WaSwz; }
    else if (id < Na + Nd){ which = 1; lid = id - Na; NKT = 80; dst = A.WdSwz; }
    else if (id < Na + Nd + Nq){ which = 2; lid = id - Na - Nd; NKT = 32; dst = A.WqT; }
    else if (id < Na + Nd + Nq + Npg){ which = 3; lid = id - Na - Nd - Nq; NKT = 48; dst = A.WpgSwz; }
    else { which = 4; lid = id - Na - Nd - Nq - Npg; NKT = 2; dst = A.U2Swz; }
    int lane = lid & 63;
    size_t rem = lid >> 6;
    int kt = (int)(rem % NKT), nt = (int)(rem / NKT);
    int n = (nt << 4) + (lane & 15);
    int k0 = (kt << 5) + ((lane >> 4) << 3);
    union { u16 h[8]; uint4 u; } o;
    #pragma unroll
    for (int j = 0; j < 8; ++j){
      int k = k0 + j;
      float vv = 0.f;
      if (which == 0){
        int rr = (n & 3) * 1024 + (n >> 2);
        vv = (k < 768) ? A.Wi_a[(size_t)rr * 768 + k] : A.Wh_a[(size_t)rr * 1024 + (k - 768)];
      } else if (which == 1){
        int rr = (n & 3) * 1024 + (n >> 2);
        vv = (k < 1536) ? A.Wi_d[(size_t)rr * 1536 + k] : A.Wh_d[(size_t)rr * 1024 + (k - 1536)];
      } else if (which == 2){
        // WqT[d][k] row-major: d = lid>>7, k = (lid&127)*8 + j
        vv = A.Wq[(size_t)(lid >> 7) * 1024 + ((size_t)(lid & 127)) * 8 + j];
      } else if (which == 3){
        vv = (n < 80) ? A.Wp[(size_t)n * 1536 + k] : ((n == 80) ? A.Wg[k] : 0.f);
      } else {
        int cc = k >> 5, kk = k & 31;
        if (kk < 31){
          float s = 0.f;
          for (int f = 0; f < 32; ++f)
            s += A.Wld[(size_t)n * 32 + f] * A.Wloc[(size_t)(f * 2 + cc) * 31 + kk];
          vv = s;
        }
      }
      o.h[j] = f2b(vv);
    }
    *(uint4*)(dst + lid * 8) = o.u;
  } else {
    size_t bid = id - NT;
    if (bid < 4096){
      int rr = ((int)bid & 3) * 1024 + ((int)bid >> 2);
      A.bias_a[bid] = A.bi_a[rr] + A.bh_a[rr];
    } else if (bid < 8192){
      int n = (int)bid - 4096;
      int rr = (n & 3) * 1024 + (n >> 2);
      A.bias_d[n] = A.bi_d[rr] + A.bh_d[rr];
    } else {
      int n = (int)bid - 8192;
      A.bpg[n] = (n < 80) ? A.bp[n] : ((n == 80) ? A.bg[0] : 0.f);
    }
  }
}

// ---------------- launcher ---------------------------------------------------
extern "C" void kernel_launch(void* const* d_in, const int* in_sizes, int n_in,
                              void* d_out, int out_size, void* d_ws, size_t ws_size,
                              hipStream_t stream){
  Args A;
  A.mem   = (const float*)d_in[0];
  A.dec_in= (const float*)d_in[1];
  A.mlen  = (const int*)d_in[2];
  A.W1 = (const float*)d_in[3];  A.b1 = (const float*)d_in[4];
  A.W2 = (const float*)d_in[5];  A.b2 = (const float*)d_in[6];
  A.Wi_a = (const float*)d_in[7];  A.Wh_a = (const float*)d_in[8];
  A.bi_a = (const float*)d_in[9];  A.bh_a = (const float*)d_in[10];
  A.Wq = (const float*)d_in[11]; A.Wm = (const float*)d_in[12];
  A.v_in = (const float*)d_in[13];
  A.Wloc = (const float*)d_in[14]; A.Wld = (const float*)d_in[15];
  A.Wi_d = (const float*)d_in[16]; A.Wh_d = (const float*)d_in[17];
  A.bi_d = (const float*)d_in[18]; A.bh_d = (const float*)d_in[19];
  A.Wp = (const float*)d_in[20]; A.bp = (const float*)d_in[21];
  A.Wg = (const float*)d_in[22]; A.bg = (const float*)d_in[23];

  uint8_t* w = (uint8_t*)d_ws;
  size_t cur = 0;
  auto AL = [&](size_t bytes) -> uint8_t* {
    uint8_t* p = w + cur;
    cur = (cur + bytes + 255) & ~(size_t)255;
    return p;
  };
  A.grp_cnt  = (int*)AL(8 * 16 * 4);
  A.root_cnt = (int*)AL(16 * 4);
  A.gen_root = (int*)AL(16 * 4);
  A.gen_grp  = (int*)AL(8 * 16 * 4);
  A.ab   = (u16*)AL((size_t)2 * 65536 * 2);
  A.db   = (u16*)AL((size_t)2 * 65536 * 2);
  A.hctx = (u16*)AL((size_t)2 * 64 * 512 * 2);
  size_t zbytes = cur;   // zero-initialized every launch
  A.x_all   = (u16*)AL((size_t)TDEC * 64 * 256 * 2);
  A.pmem_bf = (u16*)AL((size_t)64 * 512 * 128 * 2);
  A.WaSwz  = (u16*)AL((size_t)1792 * 4096 * 2);
  A.WdSwz  = (u16*)AL((size_t)2560 * 4096 * 2);
  A.WqT    = (u16*)AL((size_t)128 * 1024 * 2);
  A.WpgSwz = (u16*)AL((size_t)1536 * 96 * 2);
  A.U2Swz  = (u16*)AL((size_t)64 * 128 * 2);
  A.bias_a = (float*)AL(4096 * 4);
  A.bias_d = (float*)AL(4096 * 4);
  A.bpg    = (float*)AL(96 * 4);
  A.mem_bf = (u16*)AL((size_t)64 * 512 * 512 * 2);
  A.hid_bf = A.mem_bf;   // prenet temp aliases mem_bf (prenet runs before k_membf)

  float* out = (float*)d_out;
  A.out_mel  = out;
  A.out_gate = out + (size_t)64 * 800 * 80;
  A.out_align= A.out_gate + (size_t)64 * 800;

  hipMemsetAsync(d_ws, 0, zbytes, stream);
  k_prenet1<<<dim3(6400), dim3(256), 0, stream>>>(A);
  k_prenet2<<<dim3(6400), dim3(256), 0, stream>>>(A);
  k_membf<<<dim3(4096), dim3(256), 0, stream>>>(A);
  k_pmem<<<dim3(4096), dim3(256), 0, stream>>>(A);
  k_swz<<<dim3(8877), dim3(256), 0, stream>>>(A);
  k_main<<<dim3(256), dim3(256), 0, stream>>>(A);
}

// Round 3
// 55562.463 us; speedup vs baseline: 2.0222x; 2.0222x over previous
//
#include <hip/hip_runtime.h>
#include <stdint.h>

#define TDEC 800
#define NBATCH 64
#define TE 512
#define ED 512
#define NMEL 80
#define PRE 256
#define AR 1024
#define AD 128

typedef unsigned short u16;
typedef __bf16 bf16x8 __attribute__((ext_vector_type(8)));
typedef float f32x4 __attribute__((ext_vector_type(4)));

struct Args {
  // inputs
  const float *mem, *dec_in; const int *mlen;
  const float *W1, *b1, *W2, *b2;
  const float *Wi_a, *Wh_a, *bi_a, *bh_a;
  const float *Wq, *Wm, *v_in, *Wloc, *Wld;
  const float *Wi_d, *Wh_d, *bi_d, *bh_d;
  const float *Wp, *bp, *Wg, *bg;
  // control (coherent atomics only, no fences)
  int *grp_cnt, *root_cnt, *gen_root, *gen_grp, *pq_flag, *done_pad;
  float *expsum_pad;
  // state (all accessed with agent-scope relaxed atomics = sc1, L2-bypass)
  // ab/db: [2][256 blk][64 b][4 cells] u16 ; hctx: [2][64 b][512] u16
  u16 *ab, *db, *hctx;
  float *aw, *awc, *exp_e, *pq;
  // staged read-only data (normal cached loads; L2 stays hot — no fences)
  u16 *x_all, *pmem_bf, *mem_bf, *hid_bf;
  u16 *WaSwz, *WdSwz, *WqSwz, *WpgSwz, *U2Swz;
  float *bias_a, *bias_d, *bpg;
  // outputs
  float *out_mel, *out_gate, *out_align;
};

__device__ __forceinline__ float b2f(u16 h){ return __uint_as_float(((uint32_t)h) << 16); }
__device__ __forceinline__ u16 f2b(float f){
  uint32_t u = __float_as_uint(f);
  uint32_t r = (u + 0x7fffu + ((u >> 16) & 1u)) >> 16;
  return (u16)r;
}
__device__ __forceinline__ float sigm(float x){ return 1.f / (1.f + __expf(-x)); }
__device__ __forceinline__ float tanh_(float x){ float e = __expf(2.f*x); return 1.f - 2.f/(e + 1.f); }

__device__ __forceinline__ f32x4 mfma16(bf16x8 a, bf16x8 b, f32x4 c){
  return __builtin_amdgcn_mfma_f32_16x16x32_bf16(a, b, c, 0, 0, 0);
}
__device__ __forceinline__ bf16x8 ldf(const u16* p){ return *(const bf16x8*)p; }

// ---- coherent (agent-scope, relaxed) access helpers: sc1, bypass stale L2 ---
__device__ __forceinline__ unsigned long long ald64(const void* p){
  return __hip_atomic_load((const unsigned long long*)p, __ATOMIC_RELAXED, __HIP_MEMORY_SCOPE_AGENT);
}
__device__ __forceinline__ void ast64(void* p, unsigned long long v){
  __hip_atomic_store((unsigned long long*)p, v, __ATOMIC_RELAXED, __HIP_MEMORY_SCOPE_AGENT);
}
__device__ __forceinline__ float aldf(const float* p){
  return __hip_atomic_load(p, __ATOMIC_RELAXED, __HIP_MEMORY_SCOPE_AGENT);
}
__device__ __forceinline__ void astf(float* p, float v){
  __hip_atomic_store(p, v, __ATOMIC_RELAXED, __HIP_MEMORY_SCOPE_AGENT);
}
__device__ __forceinline__ void asti(int* p, int v){
  __hip_atomic_store(p, v, __ATOMIC_RELAXED, __HIP_MEMORY_SCOPE_AGENT);
}
// block-major h fragment: elems (row, c0..c0+7), c0 % 8 == 0
__device__ __forceinline__ bf16x8 ldbm(const u16* baseP, int c0, int row){
  const u16* p = baseP + (((size_t)(c0 >> 2)) << 8) + (row << 2);
  union { unsigned long long u[2]; bf16x8 v; } r;
  r.u[0] = ald64(p); r.u[1] = ald64(p + 256);
  return r.v;
}
// contiguous 16B as two coherent 8B loads
__device__ __forceinline__ bf16x8 ldct(const u16* p){
  union { unsigned long long u[2]; bf16x8 v; } r;
  r.u[0] = ald64(p); r.u[1] = ald64(p + 4);
  return r.v;
}

// ---------------- hierarchical grid barrier: NO FENCES (sc1 protocol) --------
__device__ void gbar(const Args& A, int blk, int tid, int bt){
  __syncthreads();     // drains each wave's vmcnt before s_barrier → stores visible
  if (tid == 0){
    int g = blk >> 5;
    int old = __hip_atomic_fetch_add(&A.grp_cnt[g*16], 1, __ATOMIC_RELAXED, __HIP_MEMORY_SCOPE_AGENT);
    if (old == bt*32 - 1){
      int ro = __hip_atomic_fetch_add(&A.root_cnt[0], 1, __ATOMIC_RELAXED, __HIP_MEMORY_SCOPE_AGENT);
      if (ro == bt*8 - 1){
        __hip_atomic_store(&A.gen_root[0], bt, __ATOMIC_RELAXED, __HIP_MEMORY_SCOPE_AGENT);
      } else {
        while (__hip_atomic_load(&A.gen_root[0], __ATOMIC_RELAXED, __HIP_MEMORY_SCOPE_AGENT) < bt)
          __builtin_amdgcn_s_sleep(2);
      }
      __hip_atomic_store(&A.gen_grp[g*16], bt, __ATOMIC_RELAXED, __HIP_MEMORY_SCOPE_AGENT);
    } else {
      while (__hip_atomic_load(&A.gen_grp[g*16], __ATOMIC_RELAXED, __HIP_MEMORY_SCOPE_AGENT) < bt)
        __builtin_amdgcn_s_sleep(4);
    }
  }
  __syncthreads();
}

// ---------------- Phase 1: full-K gate GEMM (16 cols/block, B in LDS) --------
// WHICH=0 attn (K=1792, 56 kt), WHICH=1 dec (K=2560, 80 kt)
template<int WHICH>
__device__ __forceinline__ void gemm16c(const Args& A, int t, int tid,
                                        const u16* sB, float* sG){
  const int pc = t & 1, pp = (t + 1) & 1;
  const int wave = tid >> 6, lane = tid & 63;
  const int row = wave*16 + (lane & 15);
  const int kg = (lane >> 4) << 3;
  const u16* abP  = A.ab + (size_t)pp * 65536;            // ah(t-1), block-major
  const u16* dbP  = A.db + (size_t)pc * 65536;            // dh(t-2), block-major
  const u16* ctxP = A.hctx + (size_t)pp * NBATCH * 512 + (size_t)row * 512;  // ctx(t-1)
  const u16* x0   = A.x_all + ((size_t)t * NBATCH + row) * PRE;
  f32x4 accE = {0.f,0.f,0.f,0.f}, accO = accE;
  #pragma unroll
  for (int kk = 0; kk < (WHICH ? 80 : 56); ++kk){
    bf16x8 a;
    if (WHICH == 0){
      if (kk < 8)       a = ldf(x0 + kk*32 + kg);                   // read-only, cached
      else if (kk < 24) a = ldct(ctxP + kk*32 + kg - 256);
      else              a = ldbm(abP, kk*32 + kg - 768, row);
    } else {
      if (kk < 32)      a = ldbm(abP, kk*32 + kg, row);
      else if (kk < 48) a = ldct(ctxP + kk*32 + kg - 1024);
      else              a = ldbm(dbP, kk*32 + kg - 1536, row);
    }
    bf16x8 w = *(const bf16x8*)(sB + ((size_t)kk*64 + lane)*8);
    if (kk & 1) accO = mfma16(a, w, accO);
    else        accE = mfma16(a, w, accE);
  }
  f32x4 acc = accE + accO;
  int r0 = wave*16 + ((lane >> 4) << 2), col = lane & 15;
  #pragma unroll
  for (int r = 0; r < 4; ++r) sG[(r0 + r)*17 + col] = acc[r];
}

// fused LSTM pointwise: thread tid owns (bb = tid&63, cell = 4*bn + tid>>6)
__device__ __forceinline__ void pwise(int tid, const float* sG, const float* b4,
                                      float& cst, u16* sH){
  int bb = tid & 63, ci = tid >> 6;
  int j4 = ci * 4;
  float gi = sG[bb*17 + j4 + 0] + b4[0];
  float gf = sG[bb*17 + j4 + 1] + b4[1];
  float gg = sG[bb*17 + j4 + 2] + b4[2];
  float go = sG[bb*17 + j4 + 3] + b4[3];
  float cn = sigm(gf) * cst + sigm(gi) * tanh_(gg);
  cst = cn;
  sH[bb*4 + ci] = f2b(sigm(go) * tanh_(cn));
}

// ---------------- P3 pieces (4 blocks per b) ---------------------------------
__device__ __forceinline__ void loc_chunk(int tl0, int tid, u16* sLoc,
                                          const float* s_awh, const float* s_awch,
                                          const bf16x8* U2reg){
  int wave = tid >> 6, lane = tid & 63;
  int tg0 = tl0 + wave*16 + (lane & 15);     // local halo coordinate
  int kk0 = (lane >> 4) << 3;
  f32x4 acc[8];
  #pragma unroll
  for (int nt = 0; nt < 8; ++nt) acc[nt] = f32x4{0.f,0.f,0.f,0.f};
  #pragma unroll
  for (int kt = 0; kt < 2; ++kt){
    const float* src = kt ? s_awch : s_awh;
    int base = tg0 - 15 + kk0;
    union { u16 h[8]; bf16x8 v; } af;
    #pragma unroll
    for (int j = 0; j < 8; ++j) af.h[j] = f2b(src[base + j]);
    #pragma unroll
    for (int nt = 0; nt < 8; ++nt) acc[nt] = mfma16(af.v, U2reg[kt*8 + nt], acc[nt]);
  }
  int rrow = wave*16 + ((lane>>4)<<2);
  #pragma unroll
  for (int nt = 0; nt < 8; ++nt){
    int d = nt*16 + (lane & 15);
    #pragma unroll
    for (int r = 0; r < 4; ++r) sLoc[(rrow + r)*132 + d] = f2b(acc[nt][r]);
  }
}

__device__ __forceinline__ float e_chunk(const Args& A, int b, int tb, int tid,
                                         const u16* sLoc, const float* s_pq,
                                         const float* s_v, int mlen){
  int tl = tid >> 2, h4 = tid & 3;
  int tg = tb + tl;
  int d0 = h4 * 32;
  const u16* prow = A.pmem_bf + ((size_t)b*TE + tg)*AD + d0;   // read-only, L2-hot
  const u16* lrow = sLoc + tl*132 + d0;
  float s = 0.f;
  #pragma unroll
  for (int dq = 0; dq < 4; ++dq){
    bf16x8 pv = ldf(prow + dq*8);
    bf16x8 lv = *(const bf16x8*)(lrow + dq*8);
    #pragma unroll
    for (int j = 0; j < 8; ++j){
      int d = d0 + dq*8 + j;
      float arg = s_pq[d] + (float)lv[j] + (float)pv[j];
      s += tanh_(arg) * s_v[d];
    }
  }
  s += __shfl_xor(s, 1); s += __shfl_xor(s, 2);
  float ex = 0.f;
  if (h4 == 0 && tg < mlen) ex = __expf(s);
  if (h4 == 0) astf(&A.exp_e[(size_t)b*TE + tg], ex);
  return ex;
}

__device__ __forceinline__ void ctx_unit(const Args& A, int t, int b, int c, int tid,
                                         float inv, const float* s_exp, float* s_ctx,
                                         u16* sH16, int mlen){
  int wave = tid >> 6, lane = tid & 63;
  int dseg = lane & 15, rr = lane >> 4;
  const u16* mb = A.mem_bf + ((size_t)b*TE)*ED + c*128 + dseg*8;  // read-only, L2-hot
  float a[8] = {0.f,0.f,0.f,0.f,0.f,0.f,0.f,0.f};
  int tbase = wave * 128;
  int rem = mlen - tbase;
  int icnt = rem <= 0 ? 0 : ((rem + 3) >> 2);
  if (icnt > 32) icnt = 32;
  #pragma unroll 4
  for (int i = 0; i < icnt; ++i){
    int tt = tbase + i*4 + rr;                 // tt < 512 always; s_exp=0 beyond mlen
    float wt = s_exp[tt];
    bf16x8 mv = ldf(mb + (size_t)tt * ED);
    #pragma unroll
    for (int j = 0; j < 8; ++j) a[j] += wt * (float)mv[j];
  }
  #pragma unroll
  for (int j = 0; j < 8; ++j){ a[j] += __shfl_xor(a[j], 16); a[j] += __shfl_xor(a[j], 32); }
  if (lane < 16){
    #pragma unroll
    for (int j = 0; j < 8; ++j) s_ctx[wave*128 + dseg*8 + j] = a[j];
  }
  __syncthreads();
  if (tid < 128)
    sH16[tid] = f2b((s_ctx[tid] + s_ctx[128+tid] + s_ctx[256+tid] + s_ctx[384+tid]) * inv);
  __syncthreads();
  if (tid < 32)
    ast64(A.hctx + (size_t)(t&1)*NBATCH*512 + (size_t)b*512 + c*128 + tid*4,
          *(const unsigned long long*)(sH16 + tid*4));
}

__device__ __forceinline__ void pq_unit(const Args& A, int t, int s, int tid){
  int pc = t & 1;
  int wave = tid >> 6, lane = tid & 63;
  int m = wave*16 + (lane & 15), kg = (lane >> 4) << 3;
  const u16* abP = A.ab + (size_t)pc * 65536;
  f32x4 acc = {0.f,0.f,0.f,0.f};
  #pragma unroll 8
  for (int kt = 0; kt < 32; ++kt){
    bf16x8 af = ldbm(abP, kt*32 + kg, m);
    bf16x8 bb = ldf(A.WqSwz + (((size_t)s*32 + kt)*64 + lane)*8);
    acc = mfma16(af, bb, acc);
  }
  int r0 = wave*16 + ((lane>>4)<<2);
  int d = s*16 + (lane & 15);
  #pragma unroll
  for (int r = 0; r < 4; ++r) astf(&A.pq[(size_t)(r0+r)*AD + d], acc[r]);
}

__device__ __forceinline__ void proj_unit(const Args& A, int t, int ns, int tid){
  const int pp = (t + 1) & 1;
  int wave = tid >> 6, lane = tid & 63;
  int m = wave*16 + (lane & 15), kg = (lane >> 4) << 3;
  const u16* dbP = A.db + (size_t)pp * 65536;
  const u16* cxP = A.hctx + (size_t)pp * NBATCH * 512 + (size_t)m * 512;
  int n = ns*16 + (lane & 15);
  float bv = A.bpg[n];
  f32x4 acc = {bv, bv, bv, bv};
  #pragma unroll 8
  for (int kt = 0; kt < 48; ++kt){
    bf16x8 af = (kt < 32) ? ldbm(dbP, kt*32 + kg, m) : ldct(cxP + kt*32 + kg - 1024);
    bf16x8 bb = ldf(A.WpgSwz + (((size_t)ns*48 + kt)*64 + lane)*8);
    acc = mfma16(af, bb, acc);
  }
  int r0 = wave*16 + ((lane>>4)<<2);
  #pragma unroll
  for (int r = 0; r < 4; ++r){
    int bb2 = r0 + r;
    if (n < 80)       A.out_mel[((size_t)bb2*TDEC + (t-1))*NMEL + n] = acc[r];
    else if (n == 80) A.out_gate[(size_t)bb2*TDEC + (t-1)] = acc[r];
  }
}

// ---------------- main persistent kernel -------------------------------------
__global__ __launch_bounds__(256, 1) void k_main(Args A){
  __shared__ u16 sWa[28672];                 // 56 kt x 512   (57,344 B)
  __shared__ u16 sWd[40960];                 // 80 kt x 512   (81,920 B)
  __shared__ __align__(16) char sBuf[16896]; // sGa|sGd|sHa|sHd (P1) / sLoc (P3)
  __shared__ float s_pq[128], s_v[128], s_ctx[512], s_red[4];
  __shared__ float s_exp[512];
  __shared__ float s_awh[160], s_awch[160];
  __shared__ u16 sH16[128];
  float* sGa = (float*)sBuf;
  float* sGd = (float*)(sBuf + 4352);
  u16*   sHa = (u16*)(sBuf + 8704);
  u16*   sHd = (u16*)(sBuf + 9216);
  u16*   sLoc = (u16*)sBuf;
  const int bn = blockIdx.x, tid = threadIdx.x;
  const int c = bn >> 6, b = bn & 63;
  // stage this block's 16-col weight slices (persist for all 800 steps)
  {
    const uint4* ga = (const uint4*)(A.WaSwz + (size_t)bn*28672);
    for (int i = tid; i < 3584; i += 256) ((uint4*)sWa)[i] = ga[i];
    const uint4* gd = (const uint4*)(A.WdSwz + (size_t)bn*40960);
    for (int i = tid; i < 5120; i += 256) ((uint4*)sWd)[i] = gd[i];
  }
  if (tid < 128) s_v[tid] = A.v_in[tid];
  bf16x8 U2reg[16];
  #pragma unroll
  for (int kt = 0; kt < 2; ++kt)
    #pragma unroll
    for (int nt = 0; nt < 8; ++nt)
      U2reg[kt*8 + nt] = ldf(A.U2Swz + ((size_t)((nt*2 + kt)*64 + (tid & 63)))*8);
  float ba4[4], bd4[4];
  {
    int cb = bn*16 + (tid >> 6)*4;
    #pragma unroll
    for (int g = 0; g < 4; ++g){ ba4[g] = A.bias_a[cb+g]; bd4[g] = A.bias_d[cb+g]; }
  }
  float c_a = 0.f, c_d = 0.f;
  float awc_reg0 = 0.f, awc_reg1 = 0.f;      // c==0 block's private running awc
  const int mlen = A.mlen[b];
  __syncthreads();
  int bt = 0;
  #pragma unroll 1
  for (int t = 0; t <= TDEC; ++t){
    // ---- Phase 1: both LSTM gate GEMMs, fully in-block ----
    if (t < TDEC) gemm16c<0>(A, t, tid, sWa, sGa);
    if (t >= 1)   gemm16c<1>(A, t, tid, sWd, sGd);
    __syncthreads();
    if (t < TDEC) pwise(tid, sGa, ba4, c_a, sHa);
    if (t >= 1)   pwise(tid, sGd, bd4, c_d, sHd);
    __syncthreads();
    if (tid < 64){
      if (t < TDEC)
        ast64(A.ab + (size_t)(t&1)*65536 + (size_t)bn*256 + tid*4,
              *(const unsigned long long*)(sHa + tid*4));
    } else if (tid < 128){
      if (t >= 1)
        ast64(A.db + (size_t)((t+1)&1)*65536 + (size_t)bn*256 + (size_t)(tid-64)*4,
              *(const unsigned long long*)(sHd + (tid-64)*4));
    }
    if (t < TDEC && bn == 255){
      if (tid >= 128 && tid < 192) astf(&A.expsum_pad[(tid-128)*16], 0.f);
      else if (tid >= 192)         asti(&A.done_pad[(tid-192)*16], 0);
      if (tid == 128)              asti(&A.pq_flag[0], 0);
    }
    gbar(A, bn, tid, ++bt);
    // ---- Phase 3: 4 blocks per b ----
    if (t < TDEC){
      if (bn >= 64 && bn < 72){
        pq_unit(A, t, bn - 64, tid);
        __syncthreads();          // drains pq stores
        if (tid == 0)
          __hip_atomic_fetch_add(&A.pq_flag[0], 1, __ATOMIC_RELAXED, __HIP_MEMORY_SCOPE_AGENT);
      }
      if (t >= 1 && bn >= 72 && bn < 78) proj_unit(A, t, bn - 72, tid);
      const int tb = c * 128;
      const bool w0 = tb < mlen, w1 = (tb + 64) < mlen;
      if (w0){
        for (int i = tid; i < 160; i += 256){
          int idx = tb - 15 + i;
          bool v = (idx >= 0 && idx < TE);
          s_awh[i]  = v ? aldf(&A.aw[(size_t)b*TE + idx]) : 0.f;
          s_awch[i] = v ? aldf(&A.awc[(size_t)b*TE + idx]) : 0.f;
        }
      }
      __syncthreads();
      float ws = 0.f;
      if (w0) loc_chunk(15, tid, sLoc, s_awh, s_awch, U2reg);
      __syncthreads();
      if (tid == 0){
        while (__hip_atomic_load(&A.pq_flag[0], __ATOMIC_RELAXED, __HIP_MEMORY_SCOPE_AGENT) < 8)
          __builtin_amdgcn_s_sleep(8);
      }
      __syncthreads();
      if (tid < 128) s_pq[tid] = aldf(&A.pq[(size_t)b*AD + tid]);
      __syncthreads();
      if (w0) ws = e_chunk(A, b, tb, tid, sLoc, s_pq, s_v, mlen);
      __syncthreads();
      if (w1){
        loc_chunk(79, tid, sLoc, s_awh, s_awch, U2reg);
        __syncthreads();
        ws += e_chunk(A, b, tb + 64, tid, sLoc, s_pq, s_v, mlen);
      }
      #pragma unroll
      for (int o = 32; o >= 1; o >>= 1) ws += __shfl_xor(ws, o);
      if ((tid & 63) == 0) s_red[tid >> 6] = ws;
      __syncthreads();
      if (tid == 0){
        float tot = s_red[0] + s_red[1] + s_red[2] + s_red[3];
        __hip_atomic_fetch_add(&A.expsum_pad[b*16], tot, __ATOMIC_RELAXED, __HIP_MEMORY_SCOPE_AGENT);
        asm volatile("s_waitcnt vmcnt(0)" ::: "memory");   // expsum add globally done
        __hip_atomic_fetch_add(&A.done_pad[b*16], 1, __ATOMIC_RELAXED, __HIP_MEMORY_SCOPE_AGENT);
        while (__hip_atomic_load(&A.done_pad[b*16], __ATOMIC_RELAXED, __HIP_MEMORY_SCOPE_AGENT) < 4)
          __builtin_amdgcn_s_sleep(4);
      }
      __syncthreads();
      float inv = 1.f / aldf(&A.expsum_pad[b*16]);
      for (int i = tid; i < TE; i += 256)
        s_exp[i] = aldf(&A.exp_e[(size_t)b*TE + i]);
      __syncthreads();
      ctx_unit(A, t, b, c, tid, inv, s_exp, s_ctx, sH16, mlen);
      if (c == 0){
        float awt0 = s_exp[tid] * inv;
        float awt1 = s_exp[tid + 256] * inv;
        astf(&A.aw[(size_t)b*TE + tid], awt0);
        astf(&A.aw[(size_t)b*TE + tid + 256], awt1);
        awc_reg0 += awt0; awc_reg1 += awt1;
        astf(&A.awc[(size_t)b*TE + tid], awc_reg0);
        astf(&A.awc[(size_t)b*TE + tid + 256], awc_reg1);
        A.out_align[((size_t)b*TDEC + t)*TE + tid] = awt0;
        A.out_align[((size_t)b*TDEC + t)*TE + tid + 256] = awt1;
      }
      gbar(A, bn, tid, ++bt);
    } else {
      if (bn >= 72 && bn < 78) proj_unit(A, t, bn - 72, tid);
    }
  }
}

// ---------------- setup kernels ----------------------------------------------
__global__ void k_prenet1(Args A){
  __shared__ float din[8 * 80];
  int g0 = blockIdx.x * 8;
  for (int idx = threadIdx.x; idx < 640; idx += 256){
    int r = idx / 80, k = idx % 80;
    int row = g0 + r;
    int t = row >> 6, b = row & 63;
    din[idx] = (t == 0) ? 0.f : A.dec_in[((size_t)(t - 1) * NBATCH + b) * NMEL + k];
  }
  __syncthreads();
  int j = threadIdx.x;
  float acc[8] = {0,0,0,0,0,0,0,0};
  for (int k = 0; k < 80; ++k){
    float w = A.W1[(size_t)j * 80 + k];
    #pragma unroll
    for (int r = 0; r < 8; ++r) acc[r] += w * din[r * 80 + k];
  }
  float bb = A.b1[j];
  #pragma unroll
  for (int r = 0; r < 8; ++r){
    float vx = acc[r] + bb; if (vx < 0.f) vx = 0.f;
    A.hid_bf[(size_t)(g0 + r) * PRE + j] = f2b(vx);
  }
}

__global__ void k_prenet2(Args A){
  __shared__ float hrow[8 * 256];
  int g0 = blockIdx.x * 8;
  for (int idx = threadIdx.x; idx < 2048; idx += 256){
    int r = idx >> 8, k = idx & 255;
    hrow[idx] = b2f(A.hid_bf[(size_t)(g0 + r) * PRE + k]);
  }
  __syncthreads();
  int j = threadIdx.x;
  float acc[8] = {0,0,0,0,0,0,0,0};
  for (int k = 0; k < 256; ++k){
    float w = A.W2[(size_t)j * PRE + k];
    #pragma unroll
    for (int r = 0; r < 8; ++r) acc[r] += w * hrow[r * 256 + k];
  }
  float bb = A.b2[j];
  #pragma unroll
  for (int r = 0; r < 8; ++r){
    float vx = acc[r] + bb; if (vx < 0.f) vx = 0.f;
    A.x_all[(size_t)(g0 + r) * PRE + j] = f2b(vx);
  }
}

__global__ void k_membf(Args A){
  size_t n = (size_t)NBATCH * TE * ED;
  for (size_t i = (size_t)blockIdx.x * 256 + threadIdx.x; i < n; i += (size_t)gridDim.x * 256)
    A.mem_bf[i] = f2b(A.mem[i]);
}

__global__ void k_pmem(Args A){
  __shared__ float mrow[8 * 512];
  int g0 = blockIdx.x * 8;
  for (int idx = threadIdx.x; idx < 4096; idx += 256){
    int r = idx >> 9, k = idx & 511;
    mrow[idx] = A.mem[(size_t)(g0 + r) * ED + k];
  }
  __syncthreads();
  int d = threadIdx.x & 127, hh = threadIdx.x >> 7;
  float acc[4] = {0,0,0,0};
  for (int k = 0; k < 512; ++k){
    float w = A.Wm[(size_t)d * ED + k];
    #pragma unroll
    for (int r = 0; r < 4; ++r) acc[r] += w * mrow[(hh * 4 + r) * 512 + k];
  }
  #pragma unroll
  for (int r = 0; r < 4; ++r)
    A.pmem_bf[(size_t)(g0 + hh * 4 + r) * AD + d] = f2b(acc[r]);
}

__global__ void k_swz(Args A){
  const size_t Na = 917504, Nd = 1310720, Nq = 16384, Npg = 18432, Nu2 = 1024;
  const size_t NT = Na + Nd + Nq + Npg + Nu2;
  size_t id = (size_t)blockIdx.x * 256 + threadIdx.x;
  if (id >= NT + 8288) return;
  if (id < NT){
    int which; size_t lid; int NKT; u16* dst;
    if (id < Na){ which = 0; lid = id; NKT = 56; dst = A.WaSwz; }
    else if (id < Na + Nd){ which = 1; lid = id - Na; NKT = 80; dst = A.WdSwz; }
    else if (id < Na + Nd + Nq){ which = 2; lid = id - Na - Nd; NKT = 32; dst = A.WqSwz; }
    else if (id < Na + Nd + Nq + Npg){ which = 3; lid = id - Na - Nd - Nq; NKT = 48; dst = A.WpgSwz; }
    else { which = 4; lid = id - Na - Nd - Nq - Npg; NKT = 2; dst = A.U2Swz; }
    int lane = lid & 63;
    size_t rem = lid >> 6;
    int kt = (int)(rem % NKT), nt = (int)(rem / NKT);
    int n = (nt << 4) + (lane & 15);
    int k0 = (kt << 5) + ((lane >> 4) << 3);
    union { u16 h[8]; uint4 u; } o;
    #pragma unroll
    for (int j = 0; j < 8; ++j){
      int k = k0 + j;
      float vv = 0.f;
      if (which == 0){
        int rr = (n & 3) * 1024 + (n >> 2);
        vv = (k < 768) ? A.Wi_a[(size_t)rr * 768 + k] : A.Wh_a[(size_t)rr * 1024 + (k - 768)];
      } else if (which == 1){
        int rr = (n & 3) * 1024 + (n >> 2);
        vv = (k < 1536) ? A.Wi_d[(size_t)rr * 1536 + k] : A.Wh_d[(size_t)rr * 1024 + (k - 1536)];
      } else if (which == 2){
        vv = A.Wq[(size_t)n * 1024 + k];
      } else if (which == 3){
        vv = (n < 80) ? A.Wp[(size_t)n * 1536 + k] : ((n == 80) ? A.Wg[k] : 0.f);
      } else {
        int cc = k >> 5, kk = k & 31;
        if (kk < 31){
          float s = 0.f;
          for (int f = 0; f < 32; ++f)
            s += A.Wld[(size_t)n * 32 + f] * A.Wloc[(size_t)(f * 2 + cc) * 31 + kk];
          vv = s;
        }
      }
      o.h[j] = f2b(vv);
    }
    *(uint4*)(dst + lid * 8) = o.u;
  } else {
    size_t bid = id - NT;
    if (bid < 4096){
      int rr = ((int)bid & 3) * 1024 + ((int)bid >> 2);
      A.bias_a[bid] = A.bi_a[rr] + A.bh_a[rr];
    } else if (bid < 8192){
      int n = (int)bid - 4096;
      int rr = (n & 3) * 1024 + (n >> 2);
      A.bias_d[n] = A.bi_d[rr] + A.bh_d[rr];
    } else {
      int n = (int)bid - 8192;
      A.bpg[n] = (n < 80) ? A.bp[n] : ((n == 80) ? A.bg[0] : 0.f);
    }
  }
}

// ---------------- launcher ---------------------------------------------------
extern "C" void kernel_launch(void* const* d_in, const int* in_sizes, int n_in,
                              void* d_out, int out_size, void* d_ws, size_t ws_size,
                              hipStream_t stream){
  Args A;
  A.mem   = (const float*)d_in[0];
  A.dec_in= (const float*)d_in[1];
  A.mlen  = (const int*)d_in[2];
  A.W1 = (const float*)d_in[3];  A.b1 = (const float*)d_in[4];
  A.W2 = (const float*)d_in[5];  A.b2 = (const float*)d_in[6];
  A.Wi_a = (const float*)d_in[7];  A.Wh_a = (const float*)d_in[8];
  A.bi_a = (const float*)d_in[9];  A.bh_a = (const float*)d_in[10];
  A.Wq = (const float*)d_in[11]; A.Wm = (const float*)d_in[12];
  A.v_in = (const float*)d_in[13];
  A.Wloc = (const float*)d_in[14]; A.Wld = (const float*)d_in[15];
  A.Wi_d = (const float*)d_in[16]; A.Wh_d = (const float*)d_in[17];
  A.bi_d = (const float*)d_in[18]; A.bh_d = (const float*)d_in[19];
  A.Wp = (const float*)d_in[20]; A.bp = (const float*)d_in[21];
  A.Wg = (const float*)d_in[22]; A.bg = (const float*)d_in[23];

  uint8_t* w = (uint8_t*)d_ws;
  size_t cur = 0;
  auto AL = [&](size_t bytes) -> uint8_t* {
    uint8_t* p = w + cur;
    cur = (cur + bytes + 255) & ~(size_t)255;
    return p;
  };
  A.grp_cnt  = (int*)AL(8 * 16 * 4);
  A.root_cnt = (int*)AL(16 * 4);
  A.gen_root = (int*)AL(16 * 4);
  A.gen_grp  = (int*)AL(8 * 16 * 4);
  A.pq_flag  = (int*)AL(16 * 4);
  A.done_pad = (int*)AL(64 * 16 * 4);
  A.expsum_pad = (float*)AL(64 * 16 * 4);
  A.ab   = (u16*)AL((size_t)2 * 65536 * 2);
  A.db   = (u16*)AL((size_t)2 * 65536 * 2);
  A.hctx = (u16*)AL((size_t)2 * 64 * 512 * 2);
  A.aw   = (float*)AL((size_t)64 * 512 * 4);
  A.awc  = (float*)AL((size_t)64 * 512 * 4);
  A.exp_e= (float*)AL((size_t)64 * 512 * 4);
  size_t zbytes = cur;   // zero-initialized every launch
  A.pq      = (float*)AL((size_t)64 * 128 * 4);
  A.x_all   = (u16*)AL((size_t)TDEC * 64 * 256 * 2);
  A.pmem_bf = (u16*)AL((size_t)64 * 512 * 128 * 2);
  A.WaSwz  = (u16*)AL((size_t)1792 * 4096 * 2);
  A.WdSwz  = (u16*)AL((size_t)2560 * 4096 * 2);
  A.WqSwz  = (u16*)AL((size_t)1024 * 128 * 2);
  A.WpgSwz = (u16*)AL((size_t)1536 * 96 * 2);
  A.U2Swz  = (u16*)AL((size_t)64 * 128 * 2);
  A.bias_a = (float*)AL(4096 * 4);
  A.bias_d = (float*)AL(4096 * 4);
  A.bpg    = (float*)AL(96 * 4);
  A.mem_bf = (u16*)AL((size_t)64 * 512 * 512 * 2);
  A.hid_bf = A.mem_bf;   // prenet temp aliases mem_bf (prenet runs before k_membf)

  float* out = (float*)d_out;
  A.out_mel  = out;
  A.out_gate = out + (size_t)64 * 800 * 80;
  A.out_align= A.out_gate + (size_t)64 * 800;

  hipMemsetAsync(d_ws, 0, zbytes, stream);
  k_prenet1<<<dim3(6400), dim3(256), 0, stream>>>(A);
  k_prenet2<<<dim3(6400), dim3(256), 0, stream>>>(A);
  k_membf<<<dim3(4096), dim3(256), 0, stream>>>(A);
  k_pmem<<<dim3(4096), dim3(256), 0, stream>>>(A);
  k_swz<<<dim3(8877), dim3(256), 0, stream>>>(A);
  k_main<<<dim3(256), dim3(256), 0, stream>>>(A);
}

// Round 4
// 43342.053 us; speedup vs baseline: 2.5924x; 1.2820x over previous
//
#include <hip/hip_runtime.h>
#include <stdint.h>

#define TDEC 800
#define NBATCH 64
#define TE 512
#define ED 512
#define NMEL 80
#define PRE 256
#define AR 1024
#define AD 128

typedef unsigned short u16;
typedef __bf16 bf16x8 __attribute__((ext_vector_type(8)));
typedef float f32x4 __attribute__((ext_vector_type(4)));

struct Args {
  // inputs
  const float *mem, *dec_in; const int *mlen;
  const float *W1, *b1, *W2, *b2;
  const float *Wi_a, *Wh_a, *bi_a, *bh_a;
  const float *Wq, *Wm, *v_in, *Wloc, *Wld;
  const float *Wi_d, *Wh_d, *bi_d, *bh_d;
  const float *Wp, *bp, *Wg, *bg;
  // control (coherent atomics only, no fences)
  int *grp_cnt, *root_cnt, *gen_root, *gen_grp, *pq_flag, *done_pad;
  float *expsum_pad;
  // state (all accessed with agent-scope relaxed atomics = sc1, L2-bypass)
  // ab/db: [2][256 blk][64 b][4 cells] u16 ; hctx: [2][64 b][512] u16
  u16 *ab, *db, *hctx;
  float *aw, *awc, *exp_e, *pq;
  // staged read-only data (normal cached loads; L2 stays hot — no fences)
  u16 *x_all, *pmem_bf, *mem_bf, *hid_bf;
  u16 *WaSwz, *WdSwz, *WqSwz, *WpgSwz, *U2Swz;
  float *bias_a, *bias_d, *bpg;
  // outputs
  float *out_mel, *out_gate, *out_align;
};

__device__ __forceinline__ float b2f(u16 h){ return __uint_as_float(((uint32_t)h) << 16); }
__device__ __forceinline__ u16 f2b(float f){
  uint32_t u = __float_as_uint(f);
  uint32_t r = (u + 0x7fffu + ((u >> 16) & 1u)) >> 16;
  return (u16)r;
}
__device__ __forceinline__ float sigm(float x){ return 1.f / (1.f + __expf(-x)); }
__device__ __forceinline__ float tanh_(float x){ float e = __expf(2.f*x); return 1.f - 2.f/(e + 1.f); }

__device__ __forceinline__ f32x4 mfma16(bf16x8 a, bf16x8 b, f32x4 c){
  return __builtin_amdgcn_mfma_f32_16x16x32_bf16(a, b, c, 0, 0, 0);
}
__device__ __forceinline__ bf16x8 ldf(const u16* p){ return *(const bf16x8*)p; }

// ---- coherent (agent-scope, relaxed) access helpers: sc1, bypass stale L2 ---
__device__ __forceinline__ unsigned long long ald64(const void* p){
  return __hip_atomic_load((const unsigned long long*)p, __ATOMIC_RELAXED, __HIP_MEMORY_SCOPE_AGENT);
}
__device__ __forceinline__ void ast64(void* p, unsigned long long v){
  __hip_atomic_store((unsigned long long*)p, v, __ATOMIC_RELAXED, __HIP_MEMORY_SCOPE_AGENT);
}
__device__ __forceinline__ float aldf(const float* p){
  return __hip_atomic_load(p, __ATOMIC_RELAXED, __HIP_MEMORY_SCOPE_AGENT);
}
__device__ __forceinline__ void astf(float* p, float v){
  __hip_atomic_store(p, v, __ATOMIC_RELAXED, __HIP_MEMORY_SCOPE_AGENT);
}
__device__ __forceinline__ void asti(int* p, int v){
  __hip_atomic_store(p, v, __ATOMIC_RELAXED, __HIP_MEMORY_SCOPE_AGENT);
}
// block-major h fragment: elems (row, c0..c0+7), c0 % 8 == 0
__device__ __forceinline__ bf16x8 ldbm(const u16* baseP, int c0, int row){
  const u16* p = baseP + (((size_t)(c0 >> 2)) << 8) + (row << 2);
  union { unsigned long long u[2]; bf16x8 v; } r;
  r.u[0] = ald64(p); r.u[1] = ald64(p + 256);
  return r.v;
}
// contiguous 16B as two coherent 8B loads
__device__ __forceinline__ bf16x8 ldct(const u16* p){
  union { unsigned long long u[2]; bf16x8 v; } r;
  r.u[0] = ald64(p); r.u[1] = ald64(p + 4);
  return r.v;
}

// ---------------- hierarchical grid barrier: NO FENCES (sc1 protocol) --------
__device__ void gbar(const Args& A, int blk, int tid, int bt){
  __syncthreads();     // drains each wave's vmcnt before s_barrier → stores visible
  if (tid == 0){
    int g = blk >> 5;
    int old = __hip_atomic_fetch_add(&A.grp_cnt[g*16], 1, __ATOMIC_RELAXED, __HIP_MEMORY_SCOPE_AGENT);
    if (old == bt*32 - 1){
      int ro = __hip_atomic_fetch_add(&A.root_cnt[0], 1, __ATOMIC_RELAXED, __HIP_MEMORY_SCOPE_AGENT);
      if (ro == bt*8 - 1){
        __hip_atomic_store(&A.gen_root[0], bt, __ATOMIC_RELAXED, __HIP_MEMORY_SCOPE_AGENT);
      } else {
        while (__hip_atomic_load(&A.gen_root[0], __ATOMIC_RELAXED, __HIP_MEMORY_SCOPE_AGENT) < bt)
          __builtin_amdgcn_s_sleep(2);
      }
      __hip_atomic_store(&A.gen_grp[g*16], bt, __ATOMIC_RELAXED, __HIP_MEMORY_SCOPE_AGENT);
    } else {
      while (__hip_atomic_load(&A.gen_grp[g*16], __ATOMIC_RELAXED, __HIP_MEMORY_SCOPE_AGENT) < bt)
        __builtin_amdgcn_s_sleep(4);
    }
  }
  __syncthreads();
}

// ---------------- Phase 1: FUSED full-K gate GEMMs (16 cols/block each) ------
// One pass over the dec K-space [ah(0:1024) | ctx(1024:1536) | dh(1536:2560)];
// ah/ctx frags feed BOTH the attn-gate and dec-gate MFMAs (loaded once).
// Attn extra x-part (256 K) loaded from cached x_all.
template<bool DO_A>
__device__ __forceinline__ void gemmF(const Args& A, int t, int tid,
                                      const u16* sWa, const u16* sWd,
                                      float* sGa, float* sGd){
  const int pc = t & 1, pp = (t + 1) & 1;
  const int wave = tid >> 6, lane = tid & 63;
  const int row = wave*16 + (lane & 15);
  const int kg = (lane >> 4) << 3;
  const u16* abP  = A.ab + (size_t)pp * 65536;            // ah(t-1), block-major
  const u16* dbP  = A.db + (size_t)pc * 65536;            // dh(t-2), block-major
  const u16* ctxP = A.hctx + (size_t)pp * NBATCH * 512 + (size_t)row * 512;  // ctx(t-1)
  const u16* x0   = A.x_all + ((size_t)t * NBATCH + row) * PRE;

  f32x4 aA0 = {0.f,0.f,0.f,0.f}, aA1 = aA0, aD0 = aA0, aD1 = aA0;

  if (DO_A){
    // x-part: attn kk_a 0..7 (cached, fast)
    bf16x8 fx[8];
    #pragma unroll
    for (int j = 0; j < 8; ++j) fx[j] = ldf(x0 + j*32 + kg);
    #pragma unroll
    for (int j = 0; j < 8; ++j){
      bf16x8 w = *(const bf16x8*)(sWa + ((size_t)j*64 + lane)*8);
      if (j & 1) aA1 = mfma16(fx[j], w, aA1); else aA0 = mfma16(fx[j], w, aA0);
    }
  }
  // unified coherent frag loader over dec K-index kk in [0,80)
  auto ldfrag = [&](int kk) -> bf16x8 {
    if (kk < 32)      return ldbm(abP, kk*32 + kg, row);
    else if (kk < 48) return ldct(ctxP + (kk - 32)*32 + kg);
    else              return ldbm(dbP, (kk - 48)*32 + kg, row);
  };
  // 2x16 double-buffered prefetch: ~32 outstanding sc1 loads per wave
  bf16x8 fA[16], fB[16];
  #pragma unroll
  for (int j = 0; j < 16; ++j) fA[j] = ldfrag(j);
  #pragma unroll
  for (int B = 0; B < 5; ++B){
    const bf16x8* cur = (B & 1) ? fB : fA;
    bf16x8*       nxt = (B & 1) ? fA : fB;
    if (B < 4){
      #pragma unroll
      for (int j = 0; j < 16; ++j) nxt[j] = ldfrag((B + 1)*16 + j);
    }
    #pragma unroll
    for (int j = 0; j < 16; ++j){
      const int kk = B*16 + j;
      bf16x8 f = cur[j];
      bf16x8 wd = *(const bf16x8*)(sWd + ((size_t)kk*64 + lane)*8);
      if (kk & 1) aD1 = mfma16(f, wd, aD1); else aD0 = mfma16(f, wd, aD0);
      if (DO_A && kk < 48){
        const int ka = (kk < 32) ? (24 + kk) : (kk - 24);   // attn K-row for this frag
        bf16x8 wa = *(const bf16x8*)(sWa + ((size_t)ka*64 + lane)*8);
        if (kk & 1) aA1 = mfma16(f, wa, aA1); else aA0 = mfma16(f, wa, aA0);
      }
    }
  }
  const int r0 = wave*16 + ((lane >> 4) << 2), col = lane & 15;
  f32x4 aD = aD0 + aD1;
  #pragma unroll
  for (int r = 0; r < 4; ++r) sGd[(r0 + r)*17 + col] = aD[r];
  if (DO_A){
    f32x4 aA = aA0 + aA1;
    #pragma unroll
    for (int r = 0; r < 4; ++r) sGa[(r0 + r)*17 + col] = aA[r];
  }
}

// fused LSTM pointwise: thread tid owns (bb = tid&63, cell = 4*bn + tid>>6)
__device__ __forceinline__ void pwise(int tid, const float* sG, const float* b4,
                                      float& cst, u16* sH){
  int bb = tid & 63, ci = tid >> 6;
  int j4 = ci * 4;
  float gi = sG[bb*17 + j4 + 0] + b4[0];
  float gf = sG[bb*17 + j4 + 1] + b4[1];
  float gg = sG[bb*17 + j4 + 2] + b4[2];
  float go = sG[bb*17 + j4 + 3] + b4[3];
  float cn = sigm(gf) * cst + sigm(gi) * tanh_(gg);
  cst = cn;
  sH[bb*4 + ci] = f2b(sigm(go) * tanh_(cn));
}

// ---------------- P3 pieces (4 blocks per b) ---------------------------------
__device__ __forceinline__ void loc_chunk(int tl0, int tid, u16* sLoc,
                                          const float* s_awh, const float* s_awch,
                                          const bf16x8* U2reg){
  int wave = tid >> 6, lane = tid & 63;
  int tg0 = tl0 + wave*16 + (lane & 15);     // local halo coordinate
  int kk0 = (lane >> 4) << 3;
  f32x4 acc[8];
  #pragma unroll
  for (int nt = 0; nt < 8; ++nt) acc[nt] = f32x4{0.f,0.f,0.f,0.f};
  #pragma unroll
  for (int kt = 0; kt < 2; ++kt){
    const float* src = kt ? s_awch : s_awh;
    int base = tg0 - 15 + kk0;
    union { u16 h[8]; bf16x8 v; } af;
    #pragma unroll
    for (int j = 0; j < 8; ++j) af.h[j] = f2b(src[base + j]);
    #pragma unroll
    for (int nt = 0; nt < 8; ++nt) acc[nt] = mfma16(af.v, U2reg[kt*8 + nt], acc[nt]);
  }
  int rrow = wave*16 + ((lane>>4)<<2);
  #pragma unroll
  for (int nt = 0; nt < 8; ++nt){
    int d = nt*16 + (lane & 15);
    #pragma unroll
    for (int r = 0; r < 4; ++r) sLoc[(rrow + r)*132 + d] = f2b(acc[nt][r]);
  }
}

__device__ __forceinline__ float e_chunk(const Args& A, int b, int tb, int tid,
                                         const u16* sLoc, const float* s_pq,
                                         const float* s_v, int mlen){
  int tl = tid >> 2, h4 = tid & 3;
  int tg = tb + tl;
  int d0 = h4 * 32;
  const u16* prow = A.pmem_bf + ((size_t)b*TE + tg)*AD + d0;   // read-only, L2-hot
  const u16* lrow = sLoc + tl*132 + d0;
  float s = 0.f;
  #pragma unroll
  for (int dq = 0; dq < 4; ++dq){
    bf16x8 pv = ldf(prow + dq*8);
    bf16x8 lv = *(const bf16x8*)(lrow + dq*8);
    #pragma unroll
    for (int j = 0; j < 8; ++j){
      int d = d0 + dq*8 + j;
      float arg = s_pq[d] + (float)lv[j] + (float)pv[j];
      s += tanh_(arg) * s_v[d];
    }
  }
  s += __shfl_xor(s, 1); s += __shfl_xor(s, 2);
  float ex = 0.f;
  if (h4 == 0 && tg < mlen) ex = __expf(s);
  if (h4 == 0) astf(&A.exp_e[(size_t)b*TE + tg], ex);
  return ex;
}

__device__ __forceinline__ void ctx_unit(const Args& A, int t, int b, int c, int tid,
                                         float inv, const float* s_exp, float* s_ctx,
                                         u16* sH16, int mlen){
  int wave = tid >> 6, lane = tid & 63;
  int dseg = lane & 15, rr = lane >> 4;
  const u16* mb = A.mem_bf + ((size_t)b*TE)*ED + c*128 + dseg*8;  // read-only, L2-hot
  float a[8] = {0.f,0.f,0.f,0.f,0.f,0.f,0.f,0.f};
  int tbase = wave * 128;
  int rem = mlen - tbase;
  int icnt = rem <= 0 ? 0 : ((rem + 3) >> 2);
  if (icnt > 32) icnt = 32;
  #pragma unroll 8
  for (int i = 0; i < icnt; ++i){
    int tt = tbase + i*4 + rr;                 // tt < 512 always; s_exp=0 beyond mlen
    float wt = s_exp[tt];
    bf16x8 mv = ldf(mb + (size_t)tt * ED);
    #pragma unroll
    for (int j = 0; j < 8; ++j) a[j] += wt * (float)mv[j];
  }
  #pragma unroll
  for (int j = 0; j < 8; ++j){ a[j] += __shfl_xor(a[j], 16); a[j] += __shfl_xor(a[j], 32); }
  if (lane < 16){
    #pragma unroll
    for (int j = 0; j < 8; ++j) s_ctx[wave*128 + dseg*8 + j] = a[j];
  }
  __syncthreads();
  if (tid < 128)
    sH16[tid] = f2b((s_ctx[tid] + s_ctx[128+tid] + s_ctx[256+tid] + s_ctx[384+tid]) * inv);
  __syncthreads();
  if (tid < 32)
    ast64(A.hctx + (size_t)(t&1)*NBATCH*512 + (size_t)b*512 + c*128 + tid*4,
          *(const unsigned long long*)(sH16 + tid*4));
}

__device__ __forceinline__ void pq_unit(const Args& A, int t, int s, int tid){
  int pc = t & 1;
  int wave = tid >> 6, lane = tid & 63;
  int m = wave*16 + (lane & 15), kg = (lane >> 4) << 3;
  const u16* abP = A.ab + (size_t)pc * 65536;
  f32x4 acc = {0.f,0.f,0.f,0.f};
  #pragma unroll 8
  for (int kt = 0; kt < 32; ++kt){
    bf16x8 af = ldbm(abP, kt*32 + kg, m);
    bf16x8 bb = ldf(A.WqSwz + (((size_t)s*32 + kt)*64 + lane)*8);
    acc = mfma16(af, bb, acc);
  }
  int r0 = wave*16 + ((lane>>4)<<2);
  int d = s*16 + (lane & 15);
  #pragma unroll
  for (int r = 0; r < 4; ++r) astf(&A.pq[(size_t)(r0+r)*AD + d], acc[r]);
}

__device__ __forceinline__ void proj_unit(const Args& A, int t, int ns, int tid){
  const int pp = (t + 1) & 1;
  int wave = tid >> 6, lane = tid & 63;
  int m = wave*16 + (lane & 15), kg = (lane >> 4) << 3;
  const u16* dbP = A.db + (size_t)pp * 65536;
  const u16* cxP = A.hctx + (size_t)pp * NBATCH * 512 + (size_t)m * 512;
  int n = ns*16 + (lane & 15);
  float bv = A.bpg[n];
  f32x4 acc = {bv, bv, bv, bv};
  #pragma unroll 8
  for (int kt = 0; kt < 48; ++kt){
    bf16x8 af = (kt < 32) ? ldbm(dbP, kt*32 + kg, m) : ldct(cxP + kt*32 + kg - 1024);
    bf16x8 bb = ldf(A.WpgSwz + (((size_t)ns*48 + kt)*64 + lane)*8);
    acc = mfma16(af, bb, acc);
  }
  int r0 = wave*16 + ((lane>>4)<<2);
  #pragma unroll
  for (int r = 0; r < 4; ++r){
    int bb2 = r0 + r;
    if (n < 80)       A.out_mel[((size_t)bb2*TDEC + (t-1))*NMEL + n] = acc[r];
    else if (n == 80) A.out_gate[(size_t)bb2*TDEC + (t-1)] = acc[r];
  }
}

// ---------------- main persistent kernel -------------------------------------
__global__ __launch_bounds__(256, 1) void k_main(Args A){
  __shared__ u16 sWa[28672];                 // 56 kt x 512   (57,344 B)
  __shared__ u16 sWd[40960];                 // 80 kt x 512   (81,920 B)
  __shared__ __align__(16) char sBuf[16896]; // sGa|sGd|sHa|sHd (P1) / sLoc (P3)
  __shared__ float s_pq[128], s_v[128], s_ctx[512], s_red[4];
  __shared__ float s_exp[512];
  __shared__ float s_awh[160], s_awch[160];
  __shared__ u16 sH16[128];
  float* sGa = (float*)sBuf;
  float* sGd = (float*)(sBuf + 4352);
  u16*   sHa = (u16*)(sBuf + 8704);
  u16*   sHd = (u16*)(sBuf + 9216);
  u16*   sLoc = (u16*)sBuf;
  const int bn = blockIdx.x, tid = threadIdx.x;
  const int c = bn >> 6, b = bn & 63;
  // stage this block's 16-col weight slices (persist for all 800 steps)
  {
    const uint4* ga = (const uint4*)(A.WaSwz + (size_t)bn*28672);
    for (int i = tid; i < 3584; i += 256) ((uint4*)sWa)[i] = ga[i];
    const uint4* gd = (const uint4*)(A.WdSwz + (size_t)bn*40960);
    for (int i = tid; i < 5120; i += 256) ((uint4*)sWd)[i] = gd[i];
  }
  if (tid < 128) s_v[tid] = A.v_in[tid];
  bf16x8 U2reg[16];
  #pragma unroll
  for (int kt = 0; kt < 2; ++kt)
    #pragma unroll
    for (int nt = 0; nt < 8; ++nt)
      U2reg[kt*8 + nt] = ldf(A.U2Swz + ((size_t)((nt*2 + kt)*64 + (tid & 63)))*8);
  float ba4[4], bd4[4];
  {
    int cb = bn*16 + (tid >> 6)*4;
    #pragma unroll
    for (int g = 0; g < 4; ++g){ ba4[g] = A.bias_a[cb+g]; bd4[g] = A.bias_d[cb+g]; }
  }
  float c_a = 0.f, c_d = 0.f;
  float awc_reg0 = 0.f, awc_reg1 = 0.f;      // c==0 block's private running awc
  const int mlen = A.mlen[b];
  __syncthreads();
  int bt = 0;
  #pragma unroll 1
  for (int t = 0; t <= TDEC; ++t){
    // ---- Phase 1: fused LSTM gate GEMMs (ah/ctx loaded once) ----
    if (t < TDEC) gemmF<true >(A, t, tid, sWa, sWd, sGa, sGd);
    else          gemmF<false>(A, t, tid, sWa, sWd, sGa, sGd);
    __syncthreads();
    if (t < TDEC) pwise(tid, sGa, ba4, c_a, sHa);
    if (t >= 1)   pwise(tid, sGd, bd4, c_d, sHd);
    __syncthreads();
    if (tid < 64){
      if (t < TDEC)
        ast64(A.ab + (size_t)(t&1)*65536 + (size_t)bn*256 + tid*4,
              *(const unsigned long long*)(sHa + tid*4));
    } else if (tid < 128){
      if (t >= 1)
        ast64(A.db + (size_t)((t+1)&1)*65536 + (size_t)bn*256 + (size_t)(tid-64)*4,
              *(const unsigned long long*)(sHd + (tid-64)*4));
    }
    if (t < TDEC && bn == 255){
      if (tid >= 128 && tid < 192) astf(&A.expsum_pad[(tid-128)*16], 0.f);
      else if (tid >= 192)         asti(&A.done_pad[(tid-192)*16], 0);
      if (tid == 128)              asti(&A.pq_flag[0], 0);
    }
    gbar(A, bn, tid, ++bt);
    // ---- Phase 3: 4 blocks per b ----
    if (t < TDEC){
      if (bn >= 64 && bn < 72){
        pq_unit(A, t, bn - 64, tid);
        __syncthreads();          // drains pq stores
        if (tid == 0)
          __hip_atomic_fetch_add(&A.pq_flag[0], 1, __ATOMIC_RELAXED, __HIP_MEMORY_SCOPE_AGENT);
      }
      if (t >= 1 && bn >= 72 && bn < 78) proj_unit(A, t, bn - 72, tid);
      const int tb = c * 128;
      const bool w0 = tb < mlen, w1 = (tb + 64) < mlen;
      if (w0){
        for (int i = tid; i < 160; i += 256){
          int idx = tb - 15 + i;
          bool v = (idx >= 0 && idx < TE);
          s_awh[i]  = v ? aldf(&A.aw[(size_t)b*TE + idx]) : 0.f;
          s_awch[i] = v ? aldf(&A.awc[(size_t)b*TE + idx]) : 0.f;
        }
      }
      __syncthreads();
      float ws = 0.f;
      if (w0) loc_chunk(15, tid, sLoc, s_awh, s_awch, U2reg);
      __syncthreads();
      if (tid == 0){
        while (__hip_atomic_load(&A.pq_flag[0], __ATOMIC_RELAXED, __HIP_MEMORY_SCOPE_AGENT) < 8)
          __builtin_amdgcn_s_sleep(8);
      }
      __syncthreads();
      if (tid < 128) s_pq[tid] = aldf(&A.pq[(size_t)b*AD + tid]);
      __syncthreads();
      if (w0) ws = e_chunk(A, b, tb, tid, sLoc, s_pq, s_v, mlen);
      __syncthreads();
      if (w1){
        loc_chunk(79, tid, sLoc, s_awh, s_awch, U2reg);
        __syncthreads();
        ws += e_chunk(A, b, tb + 64, tid, sLoc, s_pq, s_v, mlen);
      }
      #pragma unroll
      for (int o = 32; o >= 1; o >>= 1) ws += __shfl_xor(ws, o);
      if ((tid & 63) == 0) s_red[tid >> 6] = ws;
      __syncthreads();
      if (tid == 0){
        float tot = s_red[0] + s_red[1] + s_red[2] + s_red[3];
        __hip_atomic_fetch_add(&A.expsum_pad[b*16], tot, __ATOMIC_RELAXED, __HIP_MEMORY_SCOPE_AGENT);
        asm volatile("s_waitcnt vmcnt(0)" ::: "memory");   // expsum add globally done
        __hip_atomic_fetch_add(&A.done_pad[b*16], 1, __ATOMIC_RELAXED, __HIP_MEMORY_SCOPE_AGENT);
        while (__hip_atomic_load(&A.done_pad[b*16], __ATOMIC_RELAXED, __HIP_MEMORY_SCOPE_AGENT) < 4)
          __builtin_amdgcn_s_sleep(4);
      }
      __syncthreads();
      float inv = 1.f / aldf(&A.expsum_pad[b*16]);
      {
        unsigned long long u = ald64(&A.exp_e[(size_t)b*TE + tid*2]);
        s_exp[tid*2]     = __uint_as_float((uint32_t)u);
        s_exp[tid*2 + 1] = __uint_as_float((uint32_t)(u >> 32));
      }
      __syncthreads();
      ctx_unit(A, t, b, c, tid, inv, s_exp, s_ctx, sH16, mlen);
      if (c == 0){
        float awt0 = s_exp[tid] * inv;
        float awt1 = s_exp[tid + 256] * inv;
        astf(&A.aw[(size_t)b*TE + tid], awt0);
        astf(&A.aw[(size_t)b*TE + tid + 256], awt1);
        awc_reg0 += awt0; awc_reg1 += awt1;
        astf(&A.awc[(size_t)b*TE + tid], awc_reg0);
        astf(&A.awc[(size_t)b*TE + tid + 256], awc_reg1);
        A.out_align[((size_t)b*TDEC + t)*TE + tid] = awt0;
        A.out_align[((size_t)b*TDEC + t)*TE + tid + 256] = awt1;
      }
      gbar(A, bn, tid, ++bt);
    } else {
      if (bn >= 72 && bn < 78) proj_unit(A, t, bn - 72, tid);
    }
  }
}

// ---------------- setup kernels ----------------------------------------------
__global__ void k_prenet1(Args A){
  __shared__ float din[8 * 80];
  int g0 = blockIdx.x * 8;
  for (int idx = threadIdx.x; idx < 640; idx += 256){
    int r = idx / 80, k = idx % 80;
    int row = g0 + r;
    int t = row >> 6, b = row & 63;
    din[idx] = (t == 0) ? 0.f : A.dec_in[((size_t)(t - 1) * NBATCH + b) * NMEL + k];
  }
  __syncthreads();
  int j = threadIdx.x;
  float acc[8] = {0,0,0,0,0,0,0,0};
  for (int k = 0; k < 80; ++k){
    float w = A.W1[(size_t)j * 80 + k];
    #pragma unroll
    for (int r = 0; r < 8; ++r) acc[r] += w * din[r * 80 + k];
  }
  float bb = A.b1[j];
  #pragma unroll
  for (int r = 0; r < 8; ++r){
    float vx = acc[r] + bb; if (vx < 0.f) vx = 0.f;
    A.hid_bf[(size_t)(g0 + r) * PRE + j] = f2b(vx);
  }
}

__global__ void k_prenet2(Args A){
  __shared__ float hrow[8 * 256];
  int g0 = blockIdx.x * 8;
  for (int idx = threadIdx.x; idx < 2048; idx += 256){
    int r = idx >> 8, k = idx & 255;
    hrow[idx] = b2f(A.hid_bf[(size_t)(g0 + r) * PRE + k]);
  }
  __syncthreads();
  int j = threadIdx.x;
  float acc[8] = {0,0,0,0,0,0,0,0};
  for (int k = 0; k < 256; ++k){
    float w = A.W2[(size_t)j * PRE + k];
    #pragma unroll
    for (int r = 0; r < 8; ++r) acc[r] += w * hrow[r * 256 + k];
  }
  float bb = A.b2[j];
  #pragma unroll
  for (int r = 0; r < 8; ++r){
    float vx = acc[r] + bb; if (vx < 0.f) vx = 0.f;
    A.x_all[(size_t)(g0 + r) * PRE + j] = f2b(vx);
  }
}

__global__ void k_membf(Args A){
  size_t n = (size_t)NBATCH * TE * ED;
  for (size_t i = (size_t)blockIdx.x * 256 + threadIdx.x; i < n; i += (size_t)gridDim.x * 256)
    A.mem_bf[i] = f2b(A.mem[i]);
}

__global__ void k_pmem(Args A){
  __shared__ float mrow[8 * 512];
  int g0 = blockIdx.x * 8;
  for (int idx = threadIdx.x; idx < 4096; idx += 256){
    int r = idx >> 9, k = idx & 511;
    mrow[idx] = A.mem[(size_t)(g0 + r) * ED + k];
  }
  __syncthreads();
  int d = threadIdx.x & 127, hh = threadIdx.x >> 7;
  float acc[4] = {0,0,0,0};
  for (int k = 0; k < 512; ++k){
    float w = A.Wm[(size_t)d * ED + k];
    #pragma unroll
    for (int r = 0; r < 4; ++r) acc[r] += w * mrow[(hh * 4 + r) * 512 + k];
  }
  #pragma unroll
  for (int r = 0; r < 4; ++r)
    A.pmem_bf[(size_t)(g0 + hh * 4 + r) * AD + d] = f2b(acc[r]);
}

__global__ void k_swz(Args A){
  const size_t Na = 917504, Nd = 1310720, Nq = 16384, Npg = 18432, Nu2 = 1024;
  const size_t NT = Na + Nd + Nq + Npg + Nu2;
  size_t id = (size_t)blockIdx.x * 256 + threadIdx.x;
  if (id >= NT + 8288) return;
  if (id < NT){
    int which; size_t lid; int NKT; u16* dst;
    if (id < Na){ which = 0; lid = id; NKT = 56; dst = A.WaSwz; }
    else if (id < Na + Nd){ which = 1; lid = id - Na; NKT = 80; dst = A.WdSwz; }
    else if (id < Na + Nd + Nq){ which = 2; lid = id - Na - Nd; NKT = 32; dst = A.WqSwz; }
    else if (id < Na + Nd + Nq + Npg){ which = 3; lid = id - Na - Nd - Nq; NKT = 48; dst = A.WpgSwz; }
    else { which = 4; lid = id - Na - Nd - Nq - Npg; NKT = 2; dst = A.U2Swz; }
    int lane = lid & 63;
    size_t rem = lid >> 6;
    int kt = (int)(rem % NKT), nt = (int)(rem / NKT);
    int n = (nt << 4) + (lane & 15);
    int k0 = (kt << 5) + ((lane >> 4) << 3);
    union { u16 h[8]; uint4 u; } o;
    #pragma unroll
    for (int j = 0; j < 8; ++j){
      int k = k0 + j;
      float vv = 0.f;
      if (which == 0){
        int rr = (n & 3) * 1024 + (n >> 2);
        vv = (k < 768) ? A.Wi_a[(size_t)rr * 768 + k] : A.Wh_a[(size_t)rr * 1024 + (k - 768)];
      } else if (which == 1){
        int rr = (n & 3) * 1024 + (n >> 2);
        vv = (k < 1536) ? A.Wi_d[(size_t)rr * 1536 + k] : A.Wh_d[(size_t)rr * 1024 + (k - 1536)];
      } else if (which == 2){
        vv = A.Wq[(size_t)n * 1024 + k];
      } else if (which == 3){
        vv = (n < 80) ? A.Wp[(size_t)n * 1536 + k] : ((n == 80) ? A.Wg[k] : 0.f);
      } else {
        int cc = k >> 5, kk = k & 31;
        if (kk < 31){
          float s = 0.f;
          for (int f = 0; f < 32; ++f)
            s += A.Wld[(size_t)n * 32 + f] * A.Wloc[(size_t)(f * 2 + cc) * 31 + kk];
          vv = s;
        }
      }
      o.h[j] = f2b(vv);
    }
    *(uint4*)(dst + lid * 8) = o.u;
  } else {
    size_t bid = id - NT;
    if (bid < 4096){
      int rr = ((int)bid & 3) * 1024 + ((int)bid >> 2);
      A.bias_a[bid] = A.bi_a[rr] + A.bh_a[rr];
    } else if (bid < 8192){
      int n = (int)bid - 4096;
      int rr = (n & 3) * 1024 + (n >> 2);
      A.bias_d[n] = A.bi_d[rr] + A.bh_d[rr];
    } else {
      int n = (int)bid - 8192;
      A.bpg[n] = (n < 80) ? A.bp[n] : ((n == 80) ? A.bg[0] : 0.f);
    }
  }
}

// ---------------- launcher ---------------------------------------------------
extern "C" void kernel_launch(void* const* d_in, const int* in_sizes, int n_in,
                              void* d_out, int out_size, void* d_ws, size_t ws_size,
                              hipStream_t stream){
  Args A;
  A.mem   = (const float*)d_in[0];
  A.dec_in= (const float*)d_in[1];
  A.mlen  = (const int*)d_in[2];
  A.W1 = (const float*)d_in[3];  A.b1 = (const float*)d_in[4];
  A.W2 = (const float*)d_in[5];  A.b2 = (const float*)d_in[6];
  A.Wi_a = (const float*)d_in[7];  A.Wh_a = (const float*)d_in[8];
  A.bi_a = (const float*)d_in[9];  A.bh_a = (const float*)d_in[10];
  A.Wq = (const float*)d_in[11]; A.Wm = (const float*)d_in[12];
  A.v_in = (const float*)d_in[13];
  A.Wloc = (const float*)d_in[14]; A.Wld = (const float*)d_in[15];
  A.Wi_d = (const float*)d_in[16]; A.Wh_d = (const float*)d_in[17];
  A.bi_d = (const float*)d_in[18]; A.bh_d = (const float*)d_in[19];
  A.Wp = (const float*)d_in[20]; A.bp = (const float*)d_in[21];
  A.Wg = (const float*)d_in[22]; A.bg = (const float*)d_in[23];

  uint8_t* w = (uint8_t*)d_ws;
  size_t cur = 0;
  auto AL = [&](size_t bytes) -> uint8_t* {
    uint8_t* p = w + cur;
    cur = (cur + bytes + 255) & ~(size_t)255;
    return p;
  };
  A.grp_cnt  = (int*)AL(8 * 16 * 4);
  A.root_cnt = (int*)AL(16 * 4);
  A.gen_root = (int*)AL(16 * 4);
  A.gen_grp  = (int*)AL(8 * 16 * 4);
  A.pq_flag  = (int*)AL(16 * 4);
  A.done_pad = (int*)AL(64 * 16 * 4);
  A.expsum_pad = (float*)AL(64 * 16 * 4);
  A.ab   = (u16*)AL((size_t)2 * 65536 * 2);
  A.db   = (u16*)AL((size_t)2 * 65536 * 2);
  A.hctx = (u16*)AL((size_t)2 * 64 * 512 * 2);
  A.aw   = (float*)AL((size_t)64 * 512 * 4);
  A.awc  = (float*)AL((size_t)64 * 512 * 4);
  A.exp_e= (float*)AL((size_t)64 * 512 * 4);
  size_t zbytes = cur;   // zero-initialized every launch
  A.pq      = (float*)AL((size_t)64 * 128 * 4);
  A.x_all   = (u16*)AL((size_t)TDEC * 64 * 256 * 2);
  A.pmem_bf = (u16*)AL((size_t)64 * 512 * 128 * 2);
  A.WaSwz  = (u16*)AL((size_t)1792 * 4096 * 2);
  A.WdSwz  = (u16*)AL((size_t)2560 * 4096 * 2);
  A.WqSwz  = (u16*)AL((size_t)1024 * 128 * 2);
  A.WpgSwz = (u16*)AL((size_t)1536 * 96 * 2);
  A.U2Swz  = (u16*)AL((size_t)64 * 128 * 2);
  A.bias_a = (float*)AL(4096 * 4);
  A.bias_d = (float*)AL(4096 * 4);
  A.bpg    = (float*)AL(96 * 4);
  A.mem_bf = (u16*)AL((size_t)64 * 512 * 512 * 2);
  A.hid_bf = A.mem_bf;   // prenet temp aliases mem_bf (prenet runs before k_membf)

  float* out = (float*)d_out;
  A.out_mel  = out;
  A.out_gate = out + (size_t)64 * 800 * 80;
  A.out_align= A.out_gate + (size_t)64 * 800;

  hipMemsetAsync(d_ws, 0, zbytes, stream);
  k_prenet1<<<dim3(6400), dim3(256), 0, stream>>>(A);
  k_prenet2<<<dim3(6400), dim3(256), 0, stream>>>(A);
  k_membf<<<dim3(4096), dim3(256), 0, stream>>>(A);
  k_pmem<<<dim3(4096), dim3(256), 0, stream>>>(A);
  k_swz<<<dim3(8877), dim3(256), 0, stream>>>(A);
  k_main<<<dim3(256), dim3(256), 0, stream>>>(A);
}

// Round 5
// 42344.052 us; speedup vs baseline: 2.6535x; 1.0236x over previous
//
#include <hip/hip_runtime.h>
#include <stdint.h>

#define TDEC 800
#define NBATCH 64
#define TE 512
#define ED 512
#define NMEL 80
#define PRE 256
#define AR 1024
#define AD 128

typedef unsigned short u16;
typedef __bf16 bf16x8 __attribute__((ext_vector_type(8)));
typedef float f32x4 __attribute__((ext_vector_type(4)));

struct Args {
  // inputs
  const float *mem, *dec_in; const int *mlen;
  const float *W1, *b1, *W2, *b2;
  const float *Wi_a, *Wh_a, *bi_a, *bh_a;
  const float *Wq, *Wm, *v_in, *Wloc, *Wld;
  const float *Wi_d, *Wh_d, *bi_d, *bh_d;
  const float *Wp, *bp, *Wg, *bg;
  // control (coherent atomics only, no fences)
  int *grp_cnt, *root_cnt, *gen_root, *gen_grp, *pq_flag, *done_pad;
  float *expsum_pad;
  // state (agent-scope sc1 access only — never touched by cached loads)
  // ab/db: [2][64 b][1024 cells] u16 ROW-MAJOR ; hctx: [2][64 b][512] u16
  u16 *ab, *db, *hctx;
  float *aw, *awc, *exp_e, *pq;
  // staged read-only data (normal cached loads; L2 stays hot — no fences)
  u16 *x_all, *pmem_bf, *mem_bf, *hid_bf;
  u16 *WaSwz, *WdSwz, *WqSwz, *WpgSwz, *U2Swz;
  float *bias_a, *bias_d, *bpg;
  // outputs
  float *out_mel, *out_gate, *out_align;
};

__device__ __forceinline__ float b2f(u16 h){ return __uint_as_float(((uint32_t)h) << 16); }
__device__ __forceinline__ u16 f2b(float f){
  uint32_t u = __float_as_uint(f);
  uint32_t r = (u + 0x7fffu + ((u >> 16) & 1u)) >> 16;
  return (u16)r;
}
__device__ __forceinline__ float sigm(float x){ return 1.f / (1.f + __expf(-x)); }
__device__ __forceinline__ float tanh_(float x){ float e = __expf(2.f*x); return 1.f - 2.f/(e + 1.f); }

__device__ __forceinline__ f32x4 mfma16(bf16x8 a, bf16x8 b, f32x4 c){
  return __builtin_amdgcn_mfma_f32_16x16x32_bf16(a, b, c, 0, 0, 0);
}
__device__ __forceinline__ bf16x8 ldf(const u16* p){ return *(const bf16x8*)p; }

// ---- coherent (agent-scope, relaxed) access helpers: sc1, bypass stale L2 ---
__device__ __forceinline__ unsigned long long ald64(const void* p){
  return __hip_atomic_load((const unsigned long long*)p, __ATOMIC_RELAXED, __HIP_MEMORY_SCOPE_AGENT);
}
__device__ __forceinline__ void ast64(void* p, unsigned long long v){
  __hip_atomic_store((unsigned long long*)p, v, __ATOMIC_RELAXED, __HIP_MEMORY_SCOPE_AGENT);
}
__device__ __forceinline__ float aldf(const float* p){
  return __hip_atomic_load(p, __ATOMIC_RELAXED, __HIP_MEMORY_SCOPE_AGENT);
}
__device__ __forceinline__ void astf(float* p, float v){
  __hip_atomic_store(p, v, __ATOMIC_RELAXED, __HIP_MEMORY_SCOPE_AGENT);
}
__device__ __forceinline__ void asti(int* p, int v){
  __hip_atomic_store(p, v, __ATOMIC_RELAXED, __HIP_MEMORY_SCOPE_AGENT);
}
// contiguous 16B as two coherent 8B loads (same cache line; compiler-pipelined)
__device__ __forceinline__ bf16x8 ldct(const u16* p){
  union { unsigned long long u[2]; bf16x8 v; } r;
  r.u[0] = ald64(p); r.u[1] = ald64(p + 4);
  return r.v;
}
// ---- 16B agent-coherent loads via inline asm (single request) ---------------
// issue-only: NO wait — caller must s_waitcnt vmcnt(N) + sched_barrier(0)
// before consuming (rule #18). Volatile asm preserves issue order.
__device__ __forceinline__ void issue16(bf16x8& r, const u16* p){
  asm volatile("global_load_dwordx4 %0, %1, off sc1" : "=v"(r) : "v"(p));
}
// single-shot 16B f32 load with inline drain (use outside counted regions)
__device__ __forceinline__ f32x4 ld16f(const float* p){
  f32x4 r;
  asm volatile("global_load_dwordx4 %0, %1, off sc1\n\ts_waitcnt vmcnt(0)"
               : "=v"(r) : "v"(p) : "memory");
  return r;
}

// ---------------- hierarchical grid barrier: NO FENCES (sc1 protocol) --------
__device__ void gbar(const Args& A, int blk, int tid, int bt){
  __syncthreads();     // drains each wave's vmcnt before s_barrier → stores visible
  if (tid == 0){
    int g = blk >> 5;
    int old = __hip_atomic_fetch_add(&A.grp_cnt[g*16], 1, __ATOMIC_RELAXED, __HIP_MEMORY_SCOPE_AGENT);
    if (old == bt*32 - 1){
      int ro = __hip_atomic_fetch_add(&A.root_cnt[0], 1, __ATOMIC_RELAXED, __HIP_MEMORY_SCOPE_AGENT);
      if (ro == bt*8 - 1){
        __hip_atomic_store(&A.gen_root[0], bt, __ATOMIC_RELAXED, __HIP_MEMORY_SCOPE_AGENT);
      } else {
        while (__hip_atomic_load(&A.gen_root[0], __ATOMIC_RELAXED, __HIP_MEMORY_SCOPE_AGENT) < bt)
          __builtin_amdgcn_s_sleep(2);
      }
      __hip_atomic_store(&A.gen_grp[g*16], bt, __ATOMIC_RELAXED, __HIP_MEMORY_SCOPE_AGENT);
    } else {
      while (__hip_atomic_load(&A.gen_grp[g*16], __ATOMIC_RELAXED, __HIP_MEMORY_SCOPE_AGENT) < bt)
        __builtin_amdgcn_s_sleep(4);
    }
  }
  __syncthreads();
}

// ---------------- Phase 1: FUSED full-K gate GEMMs (16 cols/block each) ------
// One pass over the dec K-space [ah(0:1024) | ctx(1024:1536) | dh(1536:2560)];
// ah/ctx frags feed BOTH the attn-gate and dec-gate MFMAs (loaded once, as
// single 16B sc1 requests, 2x16-deep counted-vmcnt pipeline).
template<bool DO_A>
__device__ __forceinline__ void gemmF(const Args& A, int t, int tid,
                                      const u16* sWa, const u16* sWd,
                                      float* sGa, float* sGd){
  const int pc = t & 1, pp = (t + 1) & 1;
  const int wave = tid >> 6, lane = tid & 63;
  const int row = wave*16 + (lane & 15);
  const int kg = (lane >> 4) << 3;
  const u16* abP = A.ab + (size_t)pp*65536 + (size_t)row*1024 + kg;   // ah(t-1)
  const u16* dbP = A.db + (size_t)pc*65536 + (size_t)row*1024 + kg;   // dh(t-2)
  const u16* cxP = A.hctx + (size_t)pp*32768 + (size_t)row*512 + kg;  // ctx(t-1)
  const u16* x0  = A.x_all + ((size_t)t*NBATCH + row)*PRE + kg;

  f32x4 aA0 = {0.f,0.f,0.f,0.f}, aA1 = aA0, aD0 = aA0, aD1 = aA0;

  if (DO_A){
    // x-part: attn kk_a 0..7 (cached loads, compiler-managed waits)
    bf16x8 fx[8];
    #pragma unroll
    for (int j = 0; j < 8; ++j) fx[j] = ldf(x0 + j*32);
    #pragma unroll
    for (int j = 0; j < 8; ++j){
      bf16x8 w = *(const bf16x8*)(sWa + ((size_t)j*64 + lane)*8);
      if (j & 1) aA1 = mfma16(fx[j], w, aA1); else aA0 = mfma16(fx[j], w, aA0);
    }
  }
  auto addr = [&](int kk) -> const u16* {
    return (kk < 32) ? (abP + kk*32)
         : (kk < 48) ? (cxP + (kk - 32)*32)
         :             (dbP + (kk - 48)*32);
  };
  // clean vmcnt slate: x-part (and any compiler vmem) fully drained
  asm volatile("s_waitcnt vmcnt(0)" ::: "memory");
  bf16x8 fA[16], fB[16];
  #pragma unroll
  for (int j = 0; j < 16; ++j) issue16(fA[j], addr(j));
  #pragma unroll
  for (int B = 0; B < 5; ++B){
    if (B < 4){
      bf16x8* nxt = (B & 1) ? fA : fB;
      #pragma unroll
      for (int j = 0; j < 16; ++j) issue16(nxt[j], addr((B + 1)*16 + j));
      asm volatile("s_waitcnt vmcnt(16)" ::: "memory");   // oldest 16 (cur) done
    } else {
      asm volatile("s_waitcnt vmcnt(0)" ::: "memory");
    }
    __builtin_amdgcn_sched_barrier(0);
    const bf16x8* cur = (B & 1) ? fB : fA;
    #pragma unroll
    for (int j = 0; j < 16; ++j){
      const int kk = B*16 + j;
      bf16x8 f = cur[j];
      bf16x8 wd = *(const bf16x8*)(sWd + ((size_t)kk*64 + lane)*8);
      if (kk & 1) aD1 = mfma16(f, wd, aD1); else aD0 = mfma16(f, wd, aD0);
      if (DO_A && kk < 48){
        const int ka = (kk < 32) ? (24 + kk) : (kk - 24);   // attn K-row of frag
        bf16x8 wa = *(const bf16x8*)(sWa + ((size_t)ka*64 + lane)*8);
        if (kk & 1) aA1 = mfma16(f, wa, aA1); else aA0 = mfma16(f, wa, aA0);
      }
    }
  }
  const int r0 = wave*16 + ((lane >> 4) << 2), col = lane & 15;
  f32x4 aD = aD0 + aD1;
  #pragma unroll
  for (int r = 0; r < 4; ++r) sGd[(r0 + r)*17 + col] = aD[r];
  if (DO_A){
    f32x4 aA = aA0 + aA1;
    #pragma unroll
    for (int r = 0; r < 4; ++r) sGa[(r0 + r)*17 + col] = aA[r];
  }
}

// fused LSTM pointwise: thread tid owns (bb = tid&63, cell = 4*bn + tid>>6)
__device__ __forceinline__ void pwise(int tid, const float* sG, const float* b4,
                                      float& cst, u16* sH){
  int bb = tid & 63, ci = tid >> 6;
  int j4 = ci * 4;
  float gi = sG[bb*17 + j4 + 0] + b4[0];
  float gf = sG[bb*17 + j4 + 1] + b4[1];
  float gg = sG[bb*17 + j4 + 2] + b4[2];
  float go = sG[bb*17 + j4 + 3] + b4[3];
  float cn = sigm(gf) * cst + sigm(gi) * tanh_(gg);
  cst = cn;
  sH[bb*4 + ci] = f2b(sigm(go) * tanh_(cn));
}

// ---------------- P3 pieces (4 blocks per b) ---------------------------------
__device__ __forceinline__ void loc_chunk(int tl0, int tid, u16* sLoc,
                                          const float* s_awh, const float* s_awch,
                                          const bf16x8* U2reg){
  int wave = tid >> 6, lane = tid & 63;
  int tg0 = tl0 + wave*16 + (lane & 15);     // local halo coordinate
  int kk0 = (lane >> 4) << 3;
  f32x4 acc[8];
  #pragma unroll
  for (int nt = 0; nt < 8; ++nt) acc[nt] = f32x4{0.f,0.f,0.f,0.f};
  #pragma unroll
  for (int kt = 0; kt < 2; ++kt){
    const float* src = kt ? s_awch : s_awh;
    int base = tg0 - 15 + kk0;
    union { u16 h[8]; bf16x8 v; } af;
    #pragma unroll
    for (int j = 0; j < 8; ++j) af.h[j] = f2b(src[base + j]);
    #pragma unroll
    for (int nt = 0; nt < 8; ++nt) acc[nt] = mfma16(af.v, U2reg[kt*8 + nt], acc[nt]);
  }
  int rrow = wave*16 + ((lane>>4)<<2);
  #pragma unroll
  for (int nt = 0; nt < 8; ++nt){
    int d = nt*16 + (lane & 15);
    #pragma unroll
    for (int r = 0; r < 4; ++r) sLoc[(rrow + r)*132 + d] = f2b(acc[nt][r]);
  }
}

__device__ __forceinline__ float e_chunk(const Args& A, int b, int tb, int tid,
                                         const u16* sLoc, const float* s_pq,
                                         const float* s_v, int mlen){
  int tl = tid >> 2, h4 = tid & 3;
  int tg = tb + tl;
  int d0 = h4 * 32;
  const u16* prow = A.pmem_bf + ((size_t)b*TE + tg)*AD + d0;   // read-only, L2-hot
  const u16* lrow = sLoc + tl*132 + d0;
  float s = 0.f;
  #pragma unroll
  for (int dq = 0; dq < 4; ++dq){
    bf16x8 pv = ldf(prow + dq*8);
    bf16x8 lv = *(const bf16x8*)(lrow + dq*8);
    #pragma unroll
    for (int j = 0; j < 8; ++j){
      int d = d0 + dq*8 + j;
      float arg = s_pq[d] + (float)lv[j] + (float)pv[j];
      s += tanh_(arg) * s_v[d];
    }
  }
  s += __shfl_xor(s, 1); s += __shfl_xor(s, 2);
  float ex = 0.f;
  if (h4 == 0 && tg < mlen) ex = __expf(s);
  if (h4 == 0) astf(&A.exp_e[(size_t)b*TE + tg], ex);
  return ex;
}

__device__ __forceinline__ void ctx_unit(const Args& A, int t, int b, int c, int tid,
                                         float inv, const float* s_exp, float* s_ctx,
                                         u16* sH16, int mlen){
  int wave = tid >> 6, lane = tid & 63;
  int dseg = lane & 15, rr = lane >> 4;
  const u16* mb = A.mem_bf + ((size_t)b*TE)*ED + c*128 + dseg*8;  // read-only, L2-hot
  float a[8] = {0.f,0.f,0.f,0.f,0.f,0.f,0.f,0.f};
  int tbase = wave * 128;
  int rem = mlen - tbase;
  int icnt = rem <= 0 ? 0 : ((rem + 3) >> 2);
  if (icnt > 32) icnt = 32;
  #pragma unroll 8
  for (int i = 0; i < icnt; ++i){
    int tt = tbase + i*4 + rr;                 // tt < 512 always; s_exp=0 beyond mlen
    float wt = s_exp[tt];
    bf16x8 mv = ldf(mb + (size_t)tt * ED);
    #pragma unroll
    for (int j = 0; j < 8; ++j) a[j] += wt * (float)mv[j];
  }
  #pragma unroll
  for (int j = 0; j < 8; ++j){ a[j] += __shfl_xor(a[j], 16); a[j] += __shfl_xor(a[j], 32); }
  if (lane < 16){
    #pragma unroll
    for (int j = 0; j < 8; ++j) s_ctx[wave*128 + dseg*8 + j] = a[j];
  }
  __syncthreads();
  if (tid < 128)
    sH16[tid] = f2b((s_ctx[tid] + s_ctx[128+tid] + s_ctx[256+tid] + s_ctx[384+tid]) * inv);
  __syncthreads();
  if (tid < 32)
    ast64(A.hctx + (size_t)(t&1)*32768 + (size_t)b*512 + c*128 + tid*4,
          *(const unsigned long long*)(sH16 + tid*4));
}

__device__ __forceinline__ void pq_unit(const Args& A, int t, int s, int tid){
  int pc = t & 1;
  int wave = tid >> 6, lane = tid & 63;
  int m = wave*16 + (lane & 15), kg = (lane >> 4) << 3;
  const u16* ap = A.ab + (size_t)pc*65536 + (size_t)m*1024 + kg;   // row-major
  f32x4 acc = {0.f,0.f,0.f,0.f};
  #pragma unroll 8
  for (int kt = 0; kt < 32; ++kt){
    bf16x8 af = ldct(ap + kt*32);
    bf16x8 bb = ldf(A.WqSwz + (((size_t)s*32 + kt)*64 + lane)*8);
    acc = mfma16(af, bb, acc);
  }
  int r0 = wave*16 + ((lane>>4)<<2);
  int d = s*16 + (lane & 15);
  #pragma unroll
  for (int r = 0; r < 4; ++r) astf(&A.pq[(size_t)(r0+r)*AD + d], acc[r]);
}

__device__ __forceinline__ void proj_unit(const Args& A, int t, int ns, int tid){
  const int pp = (t + 1) & 1;
  int wave = tid >> 6, lane = tid & 63;
  int m = wave*16 + (lane & 15), kg = (lane >> 4) << 3;
  const u16* dp = A.db + (size_t)pp*65536 + (size_t)m*1024 + kg;   // row-major
  const u16* cp = A.hctx + (size_t)pp*32768 + (size_t)m*512 + kg;
  int n = ns*16 + (lane & 15);
  float bv = A.bpg[n];
  f32x4 acc = {bv, bv, bv, bv};
  #pragma unroll 8
  for (int kt = 0; kt < 48; ++kt){
    bf16x8 af = (kt < 32) ? ldct(dp + kt*32) : ldct(cp + (kt - 32)*32);
    bf16x8 bb = ldf(A.WpgSwz + (((size_t)ns*48 + kt)*64 + lane)*8);
    acc = mfma16(af, bb, acc);
  }
  int r0 = wave*16 + ((lane>>4)<<2);
  #pragma unroll
  for (int r = 0; r < 4; ++r){
    int bb2 = r0 + r;
    if (n < 80)       A.out_mel[((size_t)bb2*TDEC + (t-1))*NMEL + n] = acc[r];
    else if (n == 80) A.out_gate[(size_t)bb2*TDEC + (t-1)] = acc[r];
  }
}

// ---------------- main persistent kernel -------------------------------------
__global__ __launch_bounds__(256, 1) void k_main(Args A){
  __shared__ u16 sWa[28672];                 // 56 kt x 512   (57,344 B)
  __shared__ u16 sWd[40960];                 // 80 kt x 512   (81,920 B)
  __shared__ __align__(16) char sBuf[16896]; // sGa|sGd|sHa|sHd (P1) / sLoc (P3)
  __shared__ float s_pq[128], s_v[128], s_ctx[512], s_red[4];
  __shared__ float s_exp[512];
  __shared__ float s_awh[160], s_awch[160];
  __shared__ u16 sH16[128];
  float* sGa = (float*)sBuf;
  float* sGd = (float*)(sBuf + 4352);
  u16*   sHa = (u16*)(sBuf + 8704);
  u16*   sHd = (u16*)(sBuf + 9216);
  u16*   sLoc = (u16*)sBuf;
  const int bn = blockIdx.x, tid = threadIdx.x;
  const int c = bn >> 6, b = bn & 63;
  // stage this block's 16-col weight slices (persist for all 800 steps)
  {
    const uint4* ga = (const uint4*)(A.WaSwz + (size_t)bn*28672);
    for (int i = tid; i < 3584; i += 256) ((uint4*)sWa)[i] = ga[i];
    const uint4* gd = (const uint4*)(A.WdSwz + (size_t)bn*40960);
    for (int i = tid; i < 5120; i += 256) ((uint4*)sWd)[i] = gd[i];
  }
  if (tid < 128) s_v[tid] = A.v_in[tid];
  bf16x8 U2reg[16];
  #pragma unroll
  for (int kt = 0; kt < 2; ++kt)
    #pragma unroll
    for (int nt = 0; nt < 8; ++nt)
      U2reg[kt*8 + nt] = ldf(A.U2Swz + ((size_t)((nt*2 + kt)*64 + (tid & 63)))*8);
  float ba4[4], bd4[4];
  {
    int cb = bn*16 + (tid >> 6)*4;
    #pragma unroll
    for (int g = 0; g < 4; ++g){ ba4[g] = A.bias_a[cb+g]; bd4[g] = A.bias_d[cb+g]; }
  }
  float c_a = 0.f, c_d = 0.f;
  float awc_reg0 = 0.f, awc_reg1 = 0.f;      // c==0 block's private running awc
  const int mlen = A.mlen[b];
  __syncthreads();
  int bt = 0;
  #pragma unroll 1
  for (int t = 0; t <= TDEC; ++t){
    // ---- Phase 1: fused LSTM gate GEMMs (ah/ctx loaded once, 16B sc1) ----
    if (t < TDEC) gemmF<true >(A, t, tid, sWa, sWd, sGa, sGd);
    else          gemmF<false>(A, t, tid, sWa, sWd, sGa, sGd);
    __syncthreads();
    if (t < TDEC) pwise(tid, sGa, ba4, c_a, sHa);
    if (t >= 1)   pwise(tid, sGd, bd4, c_d, sHd);
    __syncthreads();
    if (tid < 64){
      if (t < TDEC)
        ast64(A.ab + (size_t)(t&1)*65536 + (size_t)tid*1024 + bn*4,
              *(const unsigned long long*)(sHa + tid*4));
    } else if (tid < 128){
      if (t >= 1)
        ast64(A.db + (size_t)((t+1)&1)*65536 + (size_t)(tid-64)*1024 + bn*4,
              *(const unsigned long long*)(sHd + (tid-64)*4));
    }
    if (t < TDEC && bn == 255){
      if (tid >= 128 && tid < 192) astf(&A.expsum_pad[(tid-128)*16], 0.f);
      else if (tid >= 192)         asti(&A.done_pad[(tid-192)*16], 0);
      if (tid == 128)              asti(&A.pq_flag[0], 0);
    }
    gbar(A, bn, tid, ++bt);
    // ---- Phase 3: 4 blocks per b ----
    if (t < TDEC){
      if (bn >= 64 && bn < 72){
        pq_unit(A, t, bn - 64, tid);
        __syncthreads();          // drains pq stores
        if (tid == 0)
          __hip_atomic_fetch_add(&A.pq_flag[0], 1, __ATOMIC_RELAXED, __HIP_MEMORY_SCOPE_AGENT);
      }
      if (t >= 1 && bn >= 72 && bn < 78) proj_unit(A, t, bn - 72, tid);
      const int tb = c * 128;
      const bool w0 = tb < mlen, w1 = (tb + 64) < mlen;
      if (w0){
        for (int i = tid; i < 160; i += 256){
          int idx = tb - 15 + i;
          bool v = (idx >= 0 && idx < TE);
          s_awh[i]  = v ? aldf(&A.aw[(size_t)b*TE + idx]) : 0.f;
          s_awch[i] = v ? aldf(&A.awc[(size_t)b*TE + idx]) : 0.f;
        }
      }
      __syncthreads();
      float ws = 0.f;
      if (w0) loc_chunk(15, tid, sLoc, s_awh, s_awch, U2reg);
      __syncthreads();
      if (tid == 0){
        while (__hip_atomic_load(&A.pq_flag[0], __ATOMIC_RELAXED, __HIP_MEMORY_SCOPE_AGENT) < 8)
          __builtin_amdgcn_s_sleep(8);
      }
      __syncthreads();
      if (tid < 32)
        *(f32x4*)&s_pq[tid*4] = ld16f(&A.pq[(size_t)b*AD + tid*4]);
      __syncthreads();
      if (w0) ws = e_chunk(A, b, tb, tid, sLoc, s_pq, s_v, mlen);
      __syncthreads();
      if (w1){
        loc_chunk(79, tid, sLoc, s_awh, s_awch, U2reg);
        __syncthreads();
        ws += e_chunk(A, b, tb + 64, tid, sLoc, s_pq, s_v, mlen);
      }
      #pragma unroll
      for (int o = 32; o >= 1; o >>= 1) ws += __shfl_xor(ws, o);
      if ((tid & 63) == 0) s_red[tid >> 6] = ws;
      __syncthreads();
      if (tid == 0){
        float tot = s_red[0] + s_red[1] + s_red[2] + s_red[3];
        __hip_atomic_fetch_add(&A.expsum_pad[b*16], tot, __ATOMIC_RELAXED, __HIP_MEMORY_SCOPE_AGENT);
        asm volatile("s_waitcnt vmcnt(0)" ::: "memory");   // expsum add globally done
        __hip_atomic_fetch_add(&A.done_pad[b*16], 1, __ATOMIC_RELAXED, __HIP_MEMORY_SCOPE_AGENT);
        while (__hip_atomic_load(&A.done_pad[b*16], __ATOMIC_RELAXED, __HIP_MEMORY_SCOPE_AGENT) < 4)
          __builtin_amdgcn_s_sleep(4);
      }
      __syncthreads();
      float inv = 1.f / aldf(&A.expsum_pad[b*16]);
      if (tid < 128)
        *(f32x4*)&s_exp[tid*4] = ld16f(&A.exp_e[(size_t)b*TE + tid*4]);
      __syncthreads();
      ctx_unit(A, t, b, c, tid, inv, s_exp, s_ctx, sH16, mlen);
      if (c == 0){
        float awt0 = s_exp[tid] * inv;
        float awt1 = s_exp[tid + 256] * inv;
        astf(&A.aw[(size_t)b*TE + tid], awt0);
        astf(&A.aw[(size_t)b*TE + tid + 256], awt1);
        awc_reg0 += awt0; awc_reg1 += awt1;
        astf(&A.awc[(size_t)b*TE + tid], awc_reg0);
        astf(&A.awc[(size_t)b*TE + tid + 256], awc_reg1);
        A.out_align[((size_t)b*TDEC + t)*TE + tid] = awt0;
        A.out_align[((size_t)b*TDEC + t)*TE + tid + 256] = awt1;
      }
      gbar(A, bn, tid, ++bt);
    } else {
      if (bn >= 72 && bn < 78) proj_unit(A, t, bn - 72, tid);
    }
  }
}

// ---------------- setup kernels ----------------------------------------------
__global__ void k_prenet1(Args A){
  __shared__ float din[8 * 80];
  int g0 = blockIdx.x * 8;
  for (int idx = threadIdx.x; idx < 640; idx += 256){
    int r = idx / 80, k = idx % 80;
    int row = g0 + r;
    int t = row >> 6, b = row & 63;
    din[idx] = (t == 0) ? 0.f : A.dec_in[((size_t)(t - 1) * NBATCH + b) * NMEL + k];
  }
  __syncthreads();
  int j = threadIdx.x;
  float acc[8] = {0,0,0,0,0,0,0,0};
  for (int k = 0; k < 80; ++k){
    float w = A.W1[(size_t)j * 80 + k];
    #pragma unroll
    for (int r = 0; r < 8; ++r) acc[r] += w * din[r * 80 + k];
  }
  float bb = A.b1[j];
  #pragma unroll
  for (int r = 0; r < 8; ++r){
    float vx = acc[r] + bb; if (vx < 0.f) vx = 0.f;
    A.hid_bf[(size_t)(g0 + r) * PRE + j] = f2b(vx);
  }
}

__global__ void k_prenet2(Args A){
  __shared__ float hrow[8 * 256];
  int g0 = blockIdx.x * 8;
  for (int idx = threadIdx.x; idx < 2048; idx += 256){
    int r = idx >> 8, k = idx & 255;
    hrow[idx] = b2f(A.hid_bf[(size_t)(g0 + r) * PRE + k]);
  }
  __syncthreads();
  int j = threadIdx.x;
  float acc[8] = {0,0,0,0,0,0,0,0};
  for (int k = 0; k < 256; ++k){
    float w = A.W2[(size_t)j * PRE + k];
    #pragma unroll
    for (int r = 0; r < 8; ++r) acc[r] += w * hrow[r * 256 + k];
  }
  float bb = A.b2[j];
  #pragma unroll
  for (int r = 0; r < 8; ++r){
    float vx = acc[r] + bb; if (vx < 0.f) vx = 0.f;
    A.x_all[(size_t)(g0 + r) * PRE + j] = f2b(vx);
  }
}

__global__ void k_membf(Args A){
  size_t n = (size_t)NBATCH * TE * ED;
  for (size_t i = (size_t)blockIdx.x * 256 + threadIdx.x; i < n; i += (size_t)gridDim.x * 256)
    A.mem_bf[i] = f2b(A.mem[i]);
}

__global__ void k_pmem(Args A){
  __shared__ float mrow[8 * 512];
  int g0 = blockIdx.x * 8;
  for (int idx = threadIdx.x; idx < 4096; idx += 256){
    int r = idx >> 9, k = idx & 511;
    mrow[idx] = A.mem[(size_t)(g0 + r) * ED + k];
  }
  __syncthreads();
  int d = threadIdx.x & 127, hh = threadIdx.x >> 7;
  float acc[4] = {0,0,0,0};
  for (int k = 0; k < 512; ++k){
    float w = A.Wm[(size_t)d * ED + k];
    #pragma unroll
    for (int r = 0; r < 4; ++r) acc[r] += w * mrow[(hh * 4 + r) * 512 + k];
  }
  #pragma unroll
  for (int r = 0; r < 4; ++r)
    A.pmem_bf[(size_t)(g0 + hh * 4 + r) * AD + d] = f2b(acc[r]);
}

__global__ void k_swz(Args A){
  const size_t Na = 917504, Nd = 1310720, Nq = 16384, Npg = 18432, Nu2 = 1024;
  const size_t NT = Na + Nd + Nq + Npg + Nu2;
  size_t id = (size_t)blockIdx.x * 256 + threadIdx.x;
  if (id >= NT + 8288) return;
  if (id < NT){
    int which; size_t lid; int NKT; u16* dst;
    if (id < Na){ which = 0; lid = id; NKT = 56; dst = A.WaSwz; }
    else if (id < Na + Nd){ which = 1; lid = id - Na; NKT = 80; dst = A.WdSwz; }
    else if (id < Na + Nd + Nq){ which = 2; lid = id - Na - Nd; NKT = 32; dst = A.WqSwz; }
    else if (id < Na + Nd + Nq + Npg){ which = 3; lid = id - Na - Nd - Nq; NKT = 48; dst = A.WpgSwz; }
    else { which = 4; lid = id - Na - Nd - Nq - Npg; NKT = 2; dst = A.U2Swz; }
    int lane = lid & 63;
    size_t rem = lid >> 6;
    int kt = (int)(rem % NKT), nt = (int)(rem / NKT);
    int n = (nt << 4) + (lane & 15);
    int k0 = (kt << 5) + ((lane >> 4) << 3);
    union { u16 h[8]; uint4 u; } o;
    #pragma unroll
    for (int j = 0; j < 8; ++j){
      int k = k0 + j;
      float vv = 0.f;
      if (which == 0){
        int rr = (n & 3) * 1024 + (n >> 2);
        vv = (k < 768) ? A.Wi_a[(size_t)rr * 768 + k] : A.Wh_a[(size_t)rr * 1024 + (k - 768)];
      } else if (which == 1){
        int rr = (n & 3) * 1024 + (n >> 2);
        vv = (k < 1536) ? A.Wi_d[(size_t)rr * 1536 + k] : A.Wh_d[(size_t)rr * 1024 + (k - 1536)];
      } else if (which == 2){
        vv = A.Wq[(size_t)n * 1024 + k];
      } else if (which == 3){
        vv = (n < 80) ? A.Wp[(size_t)n * 1536 + k] : ((n == 80) ? A.Wg[k] : 0.f);
      } else {
        int cc = k >> 5, kk = k & 31;
        if (kk < 31){
          float s = 0.f;
          for (int f = 0; f < 32; ++f)
            s += A.Wld[(size_t)n * 32 + f] * A.Wloc[(size_t)(f * 2 + cc) * 31 + kk];
          vv = s;
        }
      }
      o.h[j] = f2b(vv);
    }
    *(uint4*)(dst + lid * 8) = o.u;
  } else {
    size_t bid = id - NT;
    if (bid < 4096){
      int rr = ((int)bid & 3) * 1024 + ((int)bid >> 2);
      A.bias_a[bid] = A.bi_a[rr] + A.bh_a[rr];
    } else if (bid < 8192){
      int n = (int)bid - 4096;
      int rr = (n & 3) * 1024 + (n >> 2);
      A.bias_d[n] = A.bi_d[rr] + A.bh_d[rr];
    } else {
      int n = (int)bid - 8192;
      A.bpg[n] = (n < 80) ? A.bp[n] : ((n == 80) ? A.bg[0] : 0.f);
    }
  }
}

// ---------------- launcher ---------------------------------------------------
extern "C" void kernel_launch(void* const* d_in, const int* in_sizes, int n_in,
                              void* d_out, int out_size, void* d_ws, size_t ws_size,
                              hipStream_t stream){
  Args A;
  A.mem   = (const float*)d_in[0];
  A.dec_in= (const float*)d_in[1];
  A.mlen  = (const int*)d_in[2];
  A.W1 = (const float*)d_in[3];  A.b1 = (const float*)d_in[4];
  A.W2 = (const float*)d_in[5];  A.b2 = (const float*)d_in[6];
  A.Wi_a = (const float*)d_in[7];  A.Wh_a = (const float*)d_in[8];
  A.bi_a = (const float*)d_in[9];  A.bh_a = (const float*)d_in[10];
  A.Wq = (const float*)d_in[11]; A.Wm = (const float*)d_in[12];
  A.v_in = (const float*)d_in[13];
  A.Wloc = (const float*)d_in[14]; A.Wld = (const float*)d_in[15];
  A.Wi_d = (const float*)d_in[16]; A.Wh_d = (const float*)d_in[17];
  A.bi_d = (const float*)d_in[18]; A.bh_d = (const float*)d_in[19];
  A.Wp = (const float*)d_in[20]; A.bp = (const float*)d_in[21];
  A.Wg = (const float*)d_in[22]; A.bg = (const float*)d_in[23];

  uint8_t* w = (uint8_t*)d_ws;
  size_t cur = 0;
  auto AL = [&](size_t bytes) -> uint8_t* {
    uint8_t* p = w + cur;
    cur = (cur + bytes + 255) & ~(size_t)255;
    return p;
  };
  A.grp_cnt  = (int*)AL(8 * 16 * 4);
  A.root_cnt = (int*)AL(16 * 4);
  A.gen_root = (int*)AL(16 * 4);
  A.gen_grp  = (int*)AL(8 * 16 * 4);
  A.pq_flag  = (int*)AL(16 * 4);
  A.done_pad = (int*)AL(64 * 16 * 4);
  A.expsum_pad = (float*)AL(64 * 16 * 4);
  A.ab   = (u16*)AL((size_t)2 * 65536 * 2);
  A.db   = (u16*)AL((size_t)2 * 65536 * 2);
  A.hctx = (u16*)AL((size_t)2 * 64 * 512 * 2);
  A.aw   = (float*)AL((size_t)64 * 512 * 4);
  A.awc  = (float*)AL((size_t)64 * 512 * 4);
  A.exp_e= (float*)AL((size_t)64 * 512 * 4);
  size_t zbytes = cur;   // zero-initialized every launch
  A.pq      = (float*)AL((size_t)64 * 128 * 4);
  A.x_all   = (u16*)AL((size_t)TDEC * 64 * 256 * 2);
  A.pmem_bf = (u16*)AL((size_t)64 * 512 * 128 * 2);
  A.WaSwz  = (u16*)AL((size_t)1792 * 4096 * 2);
  A.WdSwz  = (u16*)AL((size_t)2560 * 4096 * 2);
  A.WqSwz  = (u16*)AL((size_t)1024 * 128 * 2);
  A.WpgSwz = (u16*)AL((size_t)1536 * 96 * 2);
  A.U2Swz  = (u16*)AL((size_t)64 * 128 * 2);
  A.bias_a = (float*)AL(4096 * 4);
  A.bias_d = (float*)AL(4096 * 4);
  A.bpg    = (float*)AL(96 * 4);
  A.mem_bf = (u16*)AL((size_t)64 * 512 * 512 * 2);
  A.hid_bf = A.mem_bf;   // prenet temp aliases mem_bf (prenet runs before k_membf)

  float* out = (float*)d_out;
  A.out_mel  = out;
  A.out_gate = out + (size_t)64 * 800 * 80;
  A.out_align= A.out_gate + (size_t)64 * 800;

  hipMemsetAsync(d_ws, 0, zbytes, stream);
  k_prenet1<<<dim3(6400), dim3(256), 0, stream>>>(A);
  k_prenet2<<<dim3(6400), dim3(256), 0, stream>>>(A);
  k_membf<<<dim3(4096), dim3(256), 0, stream>>>(A);
  k_pmem<<<dim3(4096), dim3(256), 0, stream>>>(A);
  k_swz<<<dim3(8877), dim3(256), 0, stream>>>(A);
  k_main<<<dim3(256), dim3(256), 0, stream>>>(A);
}